// Round 1
// baseline (485.490 us; speedup 1.0000x reference)
//
#include <hip/hip_runtime.h>
#include <stdint.h>

#define NEGF (-1e30f)

typedef unsigned short ushort_t;
typedef __attribute__((ext_vector_type(8))) short short8;
typedef __attribute__((ext_vector_type(4))) float f32x4;

constexpr int cB = 4, cT = 256, cU = 64, cU1 = 65, cV = 1024, cF = 80, cH = 512, cJ = 512;
constexpr int cM = cB * cT * cU1; // 66560 = 64 * 1040

__device__ __forceinline__ unsigned short f2bf(float x){
  union { float f; unsigned int u; } c; c.f = x;
  unsigned int r = c.u + 0x7FFFu + ((c.u >> 16) & 1u);
  return (unsigned short)(r >> 16);
}

__device__ __forceinline__ float tanh_fast(float x){
  x = fminf(15.f, fmaxf(-15.f, x));
  float e = __expf(2.f * x);
  return (e - 1.f) / (e + 1.f);
}

__device__ __forceinline__ float logadd(float x, float y){
  float m = fmaxf(x, y);
  return m + __logf(1.f + __expf(-fabsf(x - y)));
}

__device__ __forceinline__ void gload16(const void* g, void* l){
  __builtin_amdgcn_global_load_lds(
      (__attribute__((address_space(1))) void*)(g),
      (__attribute__((address_space(3))) void*)(l), 16, 0, 0);
}

// ---------------- dec gather: dec[b][u] = emb[padded[b][u]] ----------------
__global__ void k_gather_dec(const float* __restrict__ emb, const int* __restrict__ targets,
                             float* __restrict__ dec){
  int row = blockIdx.x;               // 0..259
  int b = row / cU1, u = row % cU1;
  int src = (u == 0) ? 0 : targets[b * cU + (u - 1)];
  const float4* s = (const float4*)(emb + (size_t)src * cH);
  float4* d = (float4*)(dec + (size_t)row * cH);
  d[threadIdx.x] = s[threadIdx.x];    // 128 threads * float4 = 512 floats
}

// ------------- small fp32 GEMM: C[M,N] = A[M,K] @ B[K,N], 4 rows/block -------------
template<int K>
__global__ void k_gemm4(const float* __restrict__ A, const float* __restrict__ Bm,
                        float* __restrict__ C, int N){
  __shared__ float sA[4][K];
  int m0 = blockIdx.y * 4;
  int col = blockIdx.x * 256 + threadIdx.x;
  for (int i = threadIdx.x; i < 4 * K; i += 256)
    sA[i / K][i % K] = A[(size_t)(m0 + i / K) * K + (i % K)];
  __syncthreads();
  float a0 = 0.f, a1 = 0.f, a2 = 0.f, a3 = 0.f;
#pragma unroll 4
  for (int k = 0; k < K; k++){
    float bv = Bm[(size_t)k * N + col];
    a0 = fmaf(sA[0][k], bv, a0);
    a1 = fmaf(sA[1][k], bv, a1);
    a2 = fmaf(sA[2][k], bv, a2);
    a3 = fmaf(sA[3][k], bv, a3);
  }
  C[(size_t)(m0 + 0) * N + col] = a0;
  C[(size_t)(m0 + 1) * N + col] = a1;
  C[(size_t)(m0 + 2) * N + col] = a2;
  C[(size_t)(m0 + 3) * N + col] = a3;
}

// ------------- W_out (J,V) fp32 -> WT (V,J) bf16, LDS transpose -------------
__global__ void k_wt(const float* __restrict__ W_out, ushort_t* __restrict__ WT){
  __shared__ float tile[32][33];
  int j0 = blockIdx.x * 32;           // J: 512/32 = 16
  int v0 = blockIdx.y * 32;           // V: 1024/32 = 32
  int tx = threadIdx.x & 31, ty = threadIdx.x >> 5;
#pragma unroll
  for (int i = 0; i < 4; i++){
    int j = ty + i * 8;
    tile[j][tx] = W_out[(size_t)(j0 + j) * cV + v0 + tx];
  }
  __syncthreads();
#pragma unroll
  for (int i = 0; i < 4; i++){
    int v = ty + i * 8;
    WT[(size_t)(v0 + v) * cJ + j0 + tx] = f2bf(tile[tx][v]);
  }
}

// ------------- H[row][j] = bf16(tanh(e[b,t,j] + d[b,u,j] + b_j[j])) -------------
__global__ void k_h(const float* __restrict__ e, const float* __restrict__ dmat,
                    const float* __restrict__ b_j, ushort_t* __restrict__ Hb){
  int tid = threadIdx.x;
  int row = blockIdx.x * 4 + (tid >> 6);
  int j8 = (tid & 63) * 8;
  int b = row / (cT * cU1);
  int rem = row % (cT * cU1);
  int t = rem / cU1, u = rem % cU1;
  const float4* ep = (const float4*)(e + (size_t)(b * cT + t) * cJ + j8);
  const float4* dp = (const float4*)(dmat + (size_t)(b * cU1 + u) * cJ + j8);
  const float4* bp = (const float4*)(b_j + j8);
  float4 e0 = ep[0], e1 = ep[1];
  float4 d0 = dp[0], d1 = dp[1];
  float4 q0 = bp[0], q1 = bp[1];
  unsigned int x0 = (unsigned)f2bf(tanh_fast(e0.x + d0.x + q0.x)) |
                    ((unsigned)f2bf(tanh_fast(e0.y + d0.y + q0.y)) << 16);
  unsigned int x1 = (unsigned)f2bf(tanh_fast(e0.z + d0.z + q0.z)) |
                    ((unsigned)f2bf(tanh_fast(e0.w + d0.w + q0.w)) << 16);
  unsigned int x2 = (unsigned)f2bf(tanh_fast(e1.x + d1.x + q1.x)) |
                    ((unsigned)f2bf(tanh_fast(e1.y + d1.y + q1.y)) << 16);
  unsigned int x3 = (unsigned)f2bf(tanh_fast(e1.z + d1.z + q1.z)) |
                    ((unsigned)f2bf(tanh_fast(e1.w + d1.w + q1.w)) << 16);
  uint4 pack; pack.x = x0; pack.y = x1; pack.z = x2; pack.w = x3;
  *(uint4*)(Hb + (size_t)row * cJ + j8) = pack;
}

// ------------- joint GEMM + fused log-softmax gather -------------
// block: 1024 thr (16 waves); M-tile 64, N 1024 in-block, BK 32.
// wave w: cols [64w, 64w+64), all 64 rows; 4x4 tiles of mfma 16x16x32 bf16.
__global__ __launch_bounds__(1024) void k_joint(
    const ushort_t* __restrict__ Hb, const ushort_t* __restrict__ WT,
    const float* __restrict__ b_out, const int* __restrict__ targets,
    float* __restrict__ blank_lp, float* __restrict__ lbl_lp)
{
  __shared__ ushort_t sA[64 * 32];     // 4 KB
  __shared__ ushort_t sB[1024 * 32];   // 64 KB
  __shared__ float redM[16][66];
  __shared__ float redS[16][66];
  __shared__ float blankl[64];
  __shared__ float lbll[64];
  __shared__ int   tgt[64];

  int tid = threadIdx.x;
  int wid = tid >> 6, lane = tid & 63;
  int quad = lane >> 4, c16 = lane & 15;
  int wn = wid * 64;
  int rowbase = blockIdx.x * 64;

  if (tid < 64){
    int grow = rowbase + tid;
    int b = grow / (cT * cU1);
    int u = grow % cU1;
    tgt[tid] = (u < cU) ? targets[b * cU + u] : -1;
    blankl[tid] = 0.f;
    lbll[tid] = 0.f;
  }

  f32x4 acc[4][4];
#pragma unroll
  for (int i = 0; i < 4; i++)
#pragma unroll
    for (int j = 0; j < 4; j++)
      acc[i][j] = (f32x4){0.f, 0.f, 0.f, 0.f};

  // staging addresses. LDS dest is wave-uniform base + lane*16 (m104 caveat);
  // the XOR chunk swizzle is applied on the GLOBAL address so ds_read_b128
  // fragment reads are 2-way max (free, m136).
  int ar = (wid < 4) ? (wid * 16 + (lane >> 2)) : 0;
  int agc = (lane & 3) ^ ((ar >> 1) & 3);
  const ushort_t* aSrc = Hb + (size_t)(rowbase + ar) * cJ + agc * 8;
  ushort_t* aDst = sA + wid * 512;     // bytes: wid*1024
  const ushort_t* bSrc[4];
  ushort_t* bDst[4];
#pragma unroll
  for (int jj = 0; jj < 4; jj++){
    int n = wid * 64 + jj * 16 + (lane >> 2);
    int gc = (lane & 3) ^ ((n >> 1) & 3);
    bSrc[jj] = WT + (size_t)n * cJ + gc * 8;
    bDst[jj] = sB + wid * 2048 + jj * 512;
  }

  int aOff[4], bOff[4];
#pragma unroll
  for (int mt = 0; mt < 4; mt++){
    int r = mt * 16 + c16;
    aOff[mt] = r * 32 + (quad ^ ((r >> 1) & 3)) * 8;
  }
#pragma unroll
  for (int nt = 0; nt < 4; nt++){
    int n = wn + nt * 16 + c16;
    bOff[nt] = n * 32 + (quad ^ ((n >> 1) & 3)) * 8;
  }

  for (int ks = 0; ks < 16; ks++){
    int k0 = ks * 32;
    if (wid < 4) gload16(aSrc + k0, aDst);
#pragma unroll
    for (int jj = 0; jj < 4; jj++) gload16(bSrc[jj] + k0, bDst[jj]);
    __syncthreads();
    short8 af[4], bf[4];
#pragma unroll
    for (int mt = 0; mt < 4; mt++) af[mt] = *(const short8*)(sA + aOff[mt]);
#pragma unroll
    for (int nt = 0; nt < 4; nt++) bf[nt] = *(const short8*)(sB + bOff[nt]);
#pragma unroll
    for (int mt = 0; mt < 4; mt++)
#pragma unroll
      for (int nt = 0; nt < 4; nt++)
        acc[mt][nt] = __builtin_amdgcn_mfma_f32_16x16x32_bf16(af[mt], bf[nt], acc[mt][nt], 0, 0, 0);
    __syncthreads();
  }

  // epilogue: bias + blank/target gather + lse
  float bv[4];
#pragma unroll
  for (int nt = 0; nt < 4; nt++) bv[nt] = b_out[wn + nt * 16 + c16];

#pragma unroll
  for (int mt = 0; mt < 4; mt++){
#pragma unroll
    for (int r = 0; r < 4; r++){
      int row = mt * 16 + quad * 4 + r;   // C/D: col=lane&15, row=quad*4+reg (m89)
      float l0 = acc[mt][0][r] + bv[0];
      float l1 = acc[mt][1][r] + bv[1];
      float l2 = acc[mt][2][r] + bv[2];
      float l3 = acc[mt][3][r] + bv[3];
      if (wid == 0 && c16 == 0) blankl[row] = l0;
      int tg = tgt[row];
      if (wn + 0  + c16 == tg) lbll[row] = l0;
      if (wn + 16 + c16 == tg) lbll[row] = l1;
      if (wn + 32 + c16 == tg) lbll[row] = l2;
      if (wn + 48 + c16 == tg) lbll[row] = l3;
      float m = fmaxf(fmaxf(l0, l1), fmaxf(l2, l3));
      m = fmaxf(m, __shfl_xor(m, 1, 64));
      m = fmaxf(m, __shfl_xor(m, 2, 64));
      m = fmaxf(m, __shfl_xor(m, 4, 64));
      m = fmaxf(m, __shfl_xor(m, 8, 64));
      float s = __expf(l0 - m) + __expf(l1 - m) + __expf(l2 - m) + __expf(l3 - m);
      s += __shfl_xor(s, 1, 64);
      s += __shfl_xor(s, 2, 64);
      s += __shfl_xor(s, 4, 64);
      s += __shfl_xor(s, 8, 64);
      if (c16 == 0){ redM[wid][row] = m; redS[wid][row] = s; }
    }
  }
  __syncthreads();
  if (tid < 64){
    float M = -3.0e38f;
#pragma unroll
    for (int w = 0; w < 16; w++) M = fmaxf(M, redM[w][tid]);
    float S = 0.f;
#pragma unroll
    for (int w = 0; w < 16; w++) S += redS[w][tid] * __expf(redM[w][tid] - M);
    float lse = M + __logf(S);
    int grow = rowbase + tid;
    blank_lp[grow] = blankl[tid] - lse;
    lbl_lp[grow]   = lbll[tid]   - lse;
  }
}

// ------------- RNN-T alpha DP: one wave per batch, anti-diagonal wavefront -------------
__global__ void k_dp(const float* __restrict__ blank, const float* __restrict__ lbl,
                     const int* __restrict__ in_len, const int* __restrict__ tgt_len,
                     float* __restrict__ afin)
{
  int b = blockIdx.x;
  int u = threadIdx.x;                 // 0..63
  int til = in_len[b] - 1;
  int tl  = tgt_len[b];                // 32..64
  const float* bb = blank + (size_t)b * cT * cU1;
  const float* lb = lbl   + (size_t)b * cT * cU1;
  float Dprev = (u == 0) ? 0.f : NEGF; // D_d[u] = alpha[d-u][u]
  float D64prev = NEGF;
  bool cap64 = (tl == 64);

  for (int d = 1; d <= 319; d++){
    int t = d - u;
    bool tv  = (t >= 0) & (t <= cT - 1);
    bool t1v = (t >= 1) & (t <= cT - 1);
    float blv = t1v ? bb[(t - 1) * cU1 + u] : NEGF;
    float lvv = (u >= 1 && tv && (u - 1) < tl) ? lb[t * cU1 + (u - 1)] : NEGF;
    float up = __shfl_up(Dprev, 1, 64);
    float term1 = t1v ? (Dprev + blv) : NEGF;
    float term2 = (u >= 1 && tv) ? (up + lvv) : NEGF;
    float Dcur = tv ? logadd(term1, term2) : NEGF;
    if (u == tl && t == til)
      afin[b] = Dcur + bb[til * cU1 + u];
    if (cap64){
      int t64 = d - 64;
      if (t64 >= 0 && t64 <= cT - 1){
        float s63 = __shfl(Dprev, 63, 64);
        float b64v = (t64 >= 1) ? bb[(t64 - 1) * cU1 + 64] : NEGF;
        float tA = (t64 >= 1) ? (D64prev + b64v) : NEGF;
        float tB = s63 + lb[t64 * cU1 + 63];
        float D64 = logadd(tA, tB);
        if (t64 == til && u == 0)
          afin[b] = D64 + bb[til * cU1 + 64];
        D64prev = D64;
      }
    }
    Dprev = Dcur;
  }
}

__global__ void k_final(const float* __restrict__ afin, float* __restrict__ out){
  if (threadIdx.x == 0)
    out[0] = -0.25f * (afin[0] + afin[1] + afin[2] + afin[3]);
}

extern "C" void kernel_launch(void* const* d_in, const int* in_sizes, int n_in,
                              void* d_out, int out_size, void* d_ws, size_t ws_size,
                              hipStream_t stream)
{
  (void)in_sizes; (void)n_in; (void)out_size; (void)ws_size;
  const float* inputs = (const float*)d_in[0];   // (4,256,80)
  const float* W_enc  = (const float*)d_in[1];   // (80,512)
  const float* emb    = (const float*)d_in[2];   // (1024,512)
  const float* W_jenc = (const float*)d_in[3];   // (512,512)
  const float* W_jdec = (const float*)d_in[4];   // (512,512)
  const float* b_j    = (const float*)d_in[5];   // (512)
  const float* W_out  = (const float*)d_in[6];   // (512,1024)
  const float* b_out  = (const float*)d_in[7];   // (1024)
  const int* targets  = (const int*)d_in[8];     // (4,64)
  const int* in_len   = (const int*)d_in[9];     // (4)
  const int* tgt_len  = (const int*)d_in[10];    // (4)

  char* w = (char*)d_ws;
  auto alloc = [&](size_t bytes){ char* p = w; w += (bytes + 255) & ~(size_t)255; return p; };
  float* enc   = (float*)alloc((size_t)1024 * 512 * 4);
  float* e     = (float*)alloc((size_t)1024 * 512 * 4);
  float* dec   = (float*)alloc((size_t)260 * 512 * 4);
  float* dmat  = (float*)alloc((size_t)260 * 512 * 4);
  float* blank = (float*)alloc((size_t)cM * 4);
  float* lbl   = (float*)alloc((size_t)cM * 4);
  float* afin  = (float*)alloc(256);
  ushort_t* Hb = (ushort_t*)alloc((size_t)cM * 512 * 2);
  ushort_t* WT = (ushort_t*)alloc((size_t)1024 * 512 * 2);

  k_gather_dec<<<260, 128, 0, stream>>>(emb, targets, dec);
  k_gemm4<80> <<<dim3(2, 256), 256, 0, stream>>>(inputs, W_enc, enc, 512);
  k_gemm4<512><<<dim3(2, 256), 256, 0, stream>>>(enc, W_jenc, e, 512);
  k_gemm4<512><<<dim3(2, 65),  256, 0, stream>>>(dec, W_jdec, dmat, 512);
  k_wt<<<dim3(16, 32), 256, 0, stream>>>(W_out, WT);
  k_h<<<cM / 4, 256, 0, stream>>>(e, dmat, b_j, Hb);
  k_joint<<<cM / 64, 1024, 0, stream>>>(Hb, WT, b_out, targets, blank, lbl);
  k_dp<<<4, 64, 0, stream>>>(blank, lbl, in_len, tgt_len, afin);
  k_final<<<1, 64, 0, stream>>>(afin, (float*)d_out);
}

// Round 2
// 383.368 us; speedup vs baseline: 1.2664x; 1.2664x over previous
//
#include <hip/hip_runtime.h>
#include <stdint.h>

#define NEGF (-1e30f)

typedef unsigned short ushort_t;
typedef __attribute__((ext_vector_type(8))) short short8;
typedef __attribute__((ext_vector_type(4))) float f32x4;

constexpr int cB = 4, cT = 256, cU = 64, cU1 = 65, cV = 1024, cF = 80, cH = 512, cJ = 512;
constexpr int cM = cB * cT * cU1; // 66560 = 128 * 520
constexpr int cTU = cT * cU1;     // 16640

__device__ __forceinline__ unsigned short f2bf(float x){
  union { float f; unsigned int u; } c; c.f = x;
  unsigned int r = c.u + 0x7FFFu + ((c.u >> 16) & 1u);
  return (unsigned short)(r >> 16);
}

__device__ __forceinline__ float tanh_fast(float x){
  x = fminf(15.f, fmaxf(-15.f, x));
  float e = __expf(2.f * x);
  return (e - 1.f) / (e + 1.f);
}

__device__ __forceinline__ float logadd(float x, float y){
  float m = fmaxf(x, y);
  return m + __logf(1.f + __expf(-fabsf(x - y)));
}

__device__ __forceinline__ void gload16(const void* g, void* l){
  __builtin_amdgcn_global_load_lds(
      (__attribute__((address_space(1))) void*)(g),
      (__attribute__((address_space(3))) void*)(l), 16, 0, 0);
}

// ---------------- dec gather: dec[b][u] = emb[padded[b][u]] ----------------
__global__ void k_gather_dec(const float* __restrict__ emb, const int* __restrict__ targets,
                             float* __restrict__ dec){
  int row = blockIdx.x;               // 0..259
  int b = row / cU1, u = row % cU1;
  int src = (u == 0) ? 0 : targets[b * cU + (u - 1)];
  const float4* s = (const float4*)(emb + (size_t)src * cH);
  float4* d = (float4*)(dec + (size_t)row * cH);
  d[threadIdx.x] = s[threadIdx.x];    // 128 threads * float4 = 512 floats
}

// ------------- small fp32 GEMM: C[M,N] = A[M,K] @ B[K,N], 4 rows/block -------------
template<int K>
__global__ void k_gemm4(const float* __restrict__ A, const float* __restrict__ Bm,
                        float* __restrict__ C, int N){
  __shared__ float sA[4][K];
  int m0 = blockIdx.y * 4;
  int col = blockIdx.x * 256 + threadIdx.x;
  for (int i = threadIdx.x; i < 4 * K; i += 256)
    sA[i / K][i % K] = A[(size_t)(m0 + i / K) * K + (i % K)];
  __syncthreads();
  float a0 = 0.f, a1 = 0.f, a2 = 0.f, a3 = 0.f;
#pragma unroll 4
  for (int k = 0; k < K; k++){
    float bv = Bm[(size_t)k * N + col];
    a0 = fmaf(sA[0][k], bv, a0);
    a1 = fmaf(sA[1][k], bv, a1);
    a2 = fmaf(sA[2][k], bv, a2);
    a3 = fmaf(sA[3][k], bv, a3);
  }
  C[(size_t)(m0 + 0) * N + col] = a0;
  C[(size_t)(m0 + 1) * N + col] = a1;
  C[(size_t)(m0 + 2) * N + col] = a2;
  C[(size_t)(m0 + 3) * N + col] = a3;
}

// ------------- W_out (J,V) fp32 -> WT (V,J) bf16, LDS transpose -------------
__global__ void k_wt(const float* __restrict__ W_out, ushort_t* __restrict__ WT){
  __shared__ float tile[32][33];
  int j0 = blockIdx.x * 32;           // J: 512/32 = 16
  int v0 = blockIdx.y * 32;           // V: 1024/32 = 32
  int tx = threadIdx.x & 31, ty = threadIdx.x >> 5;
#pragma unroll
  for (int i = 0; i < 4; i++){
    int j = ty + i * 8;
    tile[j][tx] = W_out[(size_t)(j0 + j) * cV + v0 + tx];
  }
  __syncthreads();
#pragma unroll
  for (int i = 0; i < 4; i++){
    int v = ty + i * 8;
    WT[(size_t)(v0 + v) * cJ + j0 + tx] = f2bf(tile[tx][v]);
  }
}

// ------------- H[row][j] = bf16(tanh(e[b,t,j] + d[b,u,j] + b_j[j])) -------------
__global__ void k_h(const float* __restrict__ e, const float* __restrict__ dmat,
                    const float* __restrict__ b_j, ushort_t* __restrict__ Hb){
  int tid = threadIdx.x;
  int row = blockIdx.x * 4 + (tid >> 6);
  int j8 = (tid & 63) * 8;
  int b = row / cTU;
  int rem = row % cTU;
  int t = rem / cU1, u = rem % cU1;
  const float4* ep = (const float4*)(e + (size_t)(b * cT + t) * cJ + j8);
  const float4* dp = (const float4*)(dmat + (size_t)(b * cU1 + u) * cJ + j8);
  const float4* bp = (const float4*)(b_j + j8);
  float4 e0 = ep[0], e1 = ep[1];
  float4 d0 = dp[0], d1 = dp[1];
  float4 q0 = bp[0], q1 = bp[1];
  unsigned int x0 = (unsigned)f2bf(tanh_fast(e0.x + d0.x + q0.x)) |
                    ((unsigned)f2bf(tanh_fast(e0.y + d0.y + q0.y)) << 16);
  unsigned int x1 = (unsigned)f2bf(tanh_fast(e0.z + d0.z + q0.z)) |
                    ((unsigned)f2bf(tanh_fast(e0.w + d0.w + q0.w)) << 16);
  unsigned int x2 = (unsigned)f2bf(tanh_fast(e1.x + d1.x + q1.x)) |
                    ((unsigned)f2bf(tanh_fast(e1.y + d1.y + q1.y)) << 16);
  unsigned int x3 = (unsigned)f2bf(tanh_fast(e1.z + d1.z + q1.z)) |
                    ((unsigned)f2bf(tanh_fast(e1.w + d1.w + q1.w)) << 16);
  uint4 pack; pack.x = x0; pack.y = x1; pack.z = x2; pack.w = x3;
  *(uint4*)(Hb + (size_t)row * cJ + j8) = pack;
}

// ------------- joint GEMM + partial log-softmax (m97 shape) -------------
// 256 thr (4 waves), 128x128 tile, BK=32, 16 KB staging LDS.
// wave w: rows [(w&1)*64,+64) x cols [(w>>1)*64,+64): 4x4 mfma 16x16x32 bf16.
// grid: (8 ntiles, 520 mtiles). Writes per-block (M,S) partials + blank/label logits.
__global__ __launch_bounds__(256) void k_joint(
    const ushort_t* __restrict__ Hb, const ushort_t* __restrict__ WT,
    const float* __restrict__ b_out, const int* __restrict__ targets,
    float* __restrict__ pm, float* __restrict__ ps,   // [8][66560] n-major
    float* __restrict__ blank_g, float* __restrict__ lbl_g)
{
  __shared__ ushort_t sA[128 * 32];   // 8 KB
  __shared__ ushort_t sB[128 * 32];   // 8 KB
  __shared__ float redM[2][128];
  __shared__ float redS[2][128];
  __shared__ int tgt[128];

  int tid = threadIdx.x;
  int wid = tid >> 6, lane = tid & 63;
  int quad = lane >> 4, c16 = lane & 15;
  int wm = wid & 1, wn2 = wid >> 1;
  int bn = blockIdx.x;                // 0..7
  int bm = blockIdx.y;                // 0..519
  int rowbase = bm * 128;
  int ncol0 = bn * 128;

  if (tid < 128){
    int grow = rowbase + tid;
    int b = grow / cTU;
    int u = grow % cU1;
    tgt[tid] = (u < cU) ? targets[b * cU + u] : -1;
  }

  f32x4 acc[4][4];
#pragma unroll
  for (int i = 0; i < 4; i++)
#pragma unroll
    for (int j = 0; j < 4; j++)
      acc[i][j] = (f32x4){0.f, 0.f, 0.f, 0.f};

  // staging: instr i (0..7) covers rows [i*16, i*16+16); lane -> row i*16+(lane>>2),
  // 16B chunk (lane&3) XOR-swizzled on the GLOBAL side (LDS dst stays lane-contiguous).
  const ushort_t* aS[2]; const ushort_t* bS[2];
  ushort_t* aD[2]; ushort_t* bD[2];
#pragma unroll
  for (int s = 0; s < 2; s++){
    int i = wid * 2 + s;
    int r = i * 16 + (lane >> 2);
    int gc = (lane & 3) ^ ((r >> 1) & 3);
    aS[s] = Hb + (size_t)(rowbase + r) * cJ + gc * 8;
    bS[s] = WT + (size_t)(ncol0 + r) * cJ + gc * 8;
    aD[s] = sA + i * 512;
    bD[s] = sB + i * 512;
  }

  int aOff[4], bOff[4];
#pragma unroll
  for (int mt = 0; mt < 4; mt++){
    int r = wm * 64 + mt * 16 + c16;
    aOff[mt] = r * 32 + (quad ^ ((r >> 1) & 3)) * 8;
  }
#pragma unroll
  for (int nt = 0; nt < 4; nt++){
    int n = wn2 * 64 + nt * 16 + c16;
    bOff[nt] = n * 32 + (quad ^ ((n >> 1) & 3)) * 8;
  }

  for (int ks = 0; ks < 16; ks++){
    int k0 = ks * 32;
    gload16(aS[0] + k0, aD[0]);
    gload16(aS[1] + k0, aD[1]);
    gload16(bS[0] + k0, bD[0]);
    gload16(bS[1] + k0, bD[1]);
    __syncthreads();
    short8 af[4], bf[4];
#pragma unroll
    for (int mt = 0; mt < 4; mt++) af[mt] = *(const short8*)(sA + aOff[mt]);
#pragma unroll
    for (int nt = 0; nt < 4; nt++) bf[nt] = *(const short8*)(sB + bOff[nt]);
#pragma unroll
    for (int mt = 0; mt < 4; mt++)
#pragma unroll
      for (int nt = 0; nt < 4; nt++)
        acc[mt][nt] = __builtin_amdgcn_mfma_f32_16x16x32_bf16(af[mt], bf[nt], acc[mt][nt], 0, 0, 0);
    __syncthreads();
  }

  // epilogue: bias + blank/label gather + per-block partial (M,S)
  float bv[4];
#pragma unroll
  for (int nt = 0; nt < 4; nt++) bv[nt] = b_out[ncol0 + wn2 * 64 + nt * 16 + c16];

#pragma unroll
  for (int mt = 0; mt < 4; mt++){
#pragma unroll
    for (int r = 0; r < 4; r++){
      int rl = wm * 64 + mt * 16 + quad * 4 + r;  // C/D: col=lane&15, row=quad*4+reg (m89)
      float l0 = acc[mt][0][r] + bv[0];
      float l1 = acc[mt][1][r] + bv[1];
      float l2 = acc[mt][2][r] + bv[2];
      float l3 = acc[mt][3][r] + bv[3];
      if (bn == 0 && wn2 == 0 && c16 == 0) blank_g[rowbase + rl] = l0;
      int tg = tgt[rl];
      if (tg >= 0 && (tg >> 7) == bn){
        int tloc = tg & 127;
        int cbase = wn2 * 64 + c16;
        if (tloc == cbase)      lbl_g[rowbase + rl] = l0;
        if (tloc == cbase + 16) lbl_g[rowbase + rl] = l1;
        if (tloc == cbase + 32) lbl_g[rowbase + rl] = l2;
        if (tloc == cbase + 48) lbl_g[rowbase + rl] = l3;
      }
      float m = fmaxf(fmaxf(l0, l1), fmaxf(l2, l3));
      m = fmaxf(m, __shfl_xor(m, 1, 64));
      m = fmaxf(m, __shfl_xor(m, 2, 64));
      m = fmaxf(m, __shfl_xor(m, 4, 64));
      m = fmaxf(m, __shfl_xor(m, 8, 64));
      float s = __expf(l0 - m) + __expf(l1 - m) + __expf(l2 - m) + __expf(l3 - m);
      s += __shfl_xor(s, 1, 64);
      s += __shfl_xor(s, 2, 64);
      s += __shfl_xor(s, 4, 64);
      s += __shfl_xor(s, 8, 64);
      if (c16 == 0){ redM[wn2][rl] = m; redS[wn2][rl] = s; }
    }
  }
  __syncthreads();
  if (tid < 128){
    float m0 = redM[0][tid], m1 = redM[1][tid];
    float M = fmaxf(m0, m1);
    float S = redS[0][tid] * __expf(m0 - M) + redS[1][tid] * __expf(m1 - M);
    int grow = rowbase + tid;
    pm[(size_t)bn * cM + grow] = M;
    ps[(size_t)bn * cM + grow] = S;
  }
}

// ------------- merge 8 partials -> blank_lp / lbl_lp -------------
__global__ void k_lse(const float* __restrict__ pm, const float* __restrict__ ps,
                      const float* __restrict__ blank_g, const float* __restrict__ lbl_g,
                      float* __restrict__ blank_lp, float* __restrict__ lbl_lp){
  int row = blockIdx.x * 256 + threadIdx.x;   // 66560 = 260*256
  float m[8], s[8];
#pragma unroll
  for (int i = 0; i < 8; i++){ m[i] = pm[(size_t)i * cM + row]; s[i] = ps[(size_t)i * cM + row]; }
  float M = m[0];
#pragma unroll
  for (int i = 1; i < 8; i++) M = fmaxf(M, m[i]);
  float S = 0.f;
#pragma unroll
  for (int i = 0; i < 8; i++) S += s[i] * __expf(m[i] - M);
  float lse = M + __logf(S);
  int u = row % cU1;
  blank_lp[row] = blank_g[row] - lse;
  lbl_lp[row] = (u < cU) ? (lbl_g[row] - lse) : NEGF;
}

// ------------- RNN-T alpha DP: LDS-staged, one block per batch -------------
__global__ __launch_bounds__(256) void k_dp(
    const float* __restrict__ blank, const float* __restrict__ lbl,
    const int* __restrict__ in_len, const int* __restrict__ tgt_len,
    float* __restrict__ afin)
{
  __shared__ float sbb[cTU];   // 65 KB
  __shared__ float slb[cTU];   // 65 KB
  int b = blockIdx.x;
  const float4* bb4 = (const float4*)(blank + (size_t)b * cTU);
  const float4* lb4 = (const float4*)(lbl + (size_t)b * cTU);
  for (int i = threadIdx.x; i < cTU / 4; i += 256){
    ((float4*)sbb)[i] = bb4[i];
    ((float4*)slb)[i] = lb4[i];
  }
  __syncthreads();
  if (threadIdx.x >= 64) return;

  int u = threadIdx.x;                 // 0..63
  int til = in_len[b] - 1;
  int tl  = tgt_len[b];                // 32..64
  float Dprev = (u == 0) ? 0.f : NEGF; // D_d[u] = alpha[d-u][u]
  float D64prev = NEGF;
  bool cap64 = (tl == 64);

  for (int d = 1; d <= 319; d++){
    int t = d - u;
    bool tv  = (t >= 0) & (t <= cT - 1);
    bool t1v = (t >= 1) & (t <= cT - 1);
    float blv = t1v ? sbb[(t - 1) * cU1 + u] : NEGF;
    float lvv = (u >= 1 && tv && (u - 1) < tl) ? slb[t * cU1 + (u - 1)] : NEGF;
    float up = __shfl_up(Dprev, 1, 64);
    float term1 = t1v ? (Dprev + blv) : NEGF;
    float term2 = (u >= 1 && tv) ? (up + lvv) : NEGF;
    float Dcur = tv ? logadd(term1, term2) : NEGF;
    if (u == tl && t == til)
      afin[b] = Dcur + sbb[til * cU1 + u];
    if (cap64){
      int t64 = d - 64;
      if (t64 >= 0 && t64 <= cT - 1){
        float s63 = __shfl(Dprev, 63, 64);
        float b64v = (t64 >= 1) ? sbb[(t64 - 1) * cU1 + 64] : NEGF;
        float tA = (t64 >= 1) ? (D64prev + b64v) : NEGF;
        float tB = s63 + slb[t64 * cU1 + 63];
        float D64 = logadd(tA, tB);
        if (t64 == til && u == 0)
          afin[b] = D64 + sbb[til * cU1 + 64];
        D64prev = D64;
      }
    }
    Dprev = Dcur;
  }
}

__global__ void k_final(const float* __restrict__ afin, float* __restrict__ out){
  if (threadIdx.x == 0)
    out[0] = -0.25f * (afin[0] + afin[1] + afin[2] + afin[3]);
}

extern "C" void kernel_launch(void* const* d_in, const int* in_sizes, int n_in,
                              void* d_out, int out_size, void* d_ws, size_t ws_size,
                              hipStream_t stream)
{
  (void)in_sizes; (void)n_in; (void)out_size; (void)ws_size;
  const float* inputs = (const float*)d_in[0];   // (4,256,80)
  const float* W_enc  = (const float*)d_in[1];   // (80,512)
  const float* emb    = (const float*)d_in[2];   // (1024,512)
  const float* W_jenc = (const float*)d_in[3];   // (512,512)
  const float* W_jdec = (const float*)d_in[4];   // (512,512)
  const float* b_j    = (const float*)d_in[5];   // (512)
  const float* W_out  = (const float*)d_in[6];   // (512,1024)
  const float* b_out  = (const float*)d_in[7];   // (1024)
  const int* targets  = (const int*)d_in[8];     // (4,64)
  const int* in_len   = (const int*)d_in[9];     // (4)
  const int* tgt_len  = (const int*)d_in[10];    // (4)

  char* w = (char*)d_ws;
  auto alloc = [&](size_t bytes){ char* p = w; w += (bytes + 255) & ~(size_t)255; return p; };
  float* enc     = (float*)alloc((size_t)1024 * 512 * 4);
  float* e       = (float*)alloc((size_t)1024 * 512 * 4);
  float* dec     = (float*)alloc((size_t)260 * 512 * 4);
  float* dmat    = (float*)alloc((size_t)260 * 512 * 4);
  float* blank   = (float*)alloc((size_t)cM * 4);
  float* lbl     = (float*)alloc((size_t)cM * 4);
  float* blank_g = (float*)alloc((size_t)cM * 4);
  float* lbl_g   = (float*)alloc((size_t)cM * 4);
  float* pm      = (float*)alloc((size_t)8 * cM * 4);
  float* ps      = (float*)alloc((size_t)8 * cM * 4);
  float* afin    = (float*)alloc(256);
  ushort_t* Hb   = (ushort_t*)alloc((size_t)cM * 512 * 2);
  ushort_t* WT   = (ushort_t*)alloc((size_t)1024 * 512 * 2);

  k_gather_dec<<<260, 128, 0, stream>>>(emb, targets, dec);
  k_gemm4<80> <<<dim3(2, 256), 256, 0, stream>>>(inputs, W_enc, enc, 512);
  k_gemm4<512><<<dim3(2, 256), 256, 0, stream>>>(enc, W_jenc, e, 512);
  k_gemm4<512><<<dim3(2, 65),  256, 0, stream>>>(dec, W_jdec, dmat, 512);
  k_wt<<<dim3(16, 32), 256, 0, stream>>>(W_out, WT);
  k_h<<<cM / 4, 256, 0, stream>>>(e, dmat, b_j, Hb);
  k_joint<<<dim3(8, 520), 256, 0, stream>>>(Hb, WT, b_out, targets, pm, ps, blank_g, lbl_g);
  k_lse<<<260, 256, 0, stream>>>(pm, ps, blank_g, lbl_g, blank, lbl);
  k_dp<<<4, 256, 0, stream>>>(blank, lbl, in_len, tgt_len, afin);
  k_final<<<1, 64, 0, stream>>>(afin, (float*)d_out);
}

// Round 3
// 382.577 us; speedup vs baseline: 1.2690x; 1.0021x over previous
//
#include <hip/hip_runtime.h>
#include <stdint.h>

#define NEGF (-1e30f)

typedef unsigned short ushort_t;
typedef __attribute__((ext_vector_type(8))) short short8;
typedef __attribute__((ext_vector_type(4))) float f32x4;

constexpr int cB = 4, cT = 256, cU = 64, cU1 = 65, cV = 1024, cF = 80, cH = 512, cJ = 512;
constexpr int cM = cB * cT * cU1; // 66560 = 128 * 520
constexpr int cTU = cT * cU1;     // 16640

__device__ __forceinline__ unsigned short f2bf(float x){
  union { float f; unsigned int u; } c; c.f = x;
  unsigned int r = c.u + 0x7FFFu + ((c.u >> 16) & 1u);
  return (unsigned short)(r >> 16);
}

__device__ __forceinline__ float tanh_fast(float x){
  x = fminf(15.f, fmaxf(-15.f, x));
  float e = __expf(2.f * x);
  return (e - 1.f) / (e + 1.f);
}

__device__ __forceinline__ float logadd(float x, float y){
  float m = fmaxf(x, y);
  return m + __logf(1.f + __expf(-fabsf(x - y)));
}

// ---------------- dec gather: dec[b][u] = emb[padded[b][u]] ----------------
__global__ void k_gather_dec(const float* __restrict__ emb, const int* __restrict__ targets,
                             float* __restrict__ dec){
  int row = blockIdx.x;               // 0..259
  int b = row / cU1, u = row % cU1;
  int src = (u == 0) ? 0 : targets[b * cU + (u - 1)];
  const float4* s = (const float4*)(emb + (size_t)src * cH);
  float4* d = (float4*)(dec + (size_t)row * cH);
  d[threadIdx.x] = s[threadIdx.x];    // 128 threads * float4 = 512 floats
}

// ------------- small fp32 GEMM: C[M,N] = A[M,K] @ B[K,N] (+bias), 4 rows/block -------------
template<int K>
__global__ void k_gemm4(const float* __restrict__ A, const float* __restrict__ Bm,
                        float* __restrict__ C, int N, const float* __restrict__ bias){
  __shared__ float sA[4][K];
  int m0 = blockIdx.y * 4;
  int col = blockIdx.x * 256 + threadIdx.x;
  for (int i = threadIdx.x; i < 4 * K; i += 256)
    sA[i / K][i % K] = A[(size_t)(m0 + i / K) * K + (i % K)];
  __syncthreads();
  float a0 = 0.f, a1 = 0.f, a2 = 0.f, a3 = 0.f;
#pragma unroll 8
  for (int k = 0; k < K; k++){
    float bv = Bm[(size_t)k * N + col];
    a0 = fmaf(sA[0][k], bv, a0);
    a1 = fmaf(sA[1][k], bv, a1);
    a2 = fmaf(sA[2][k], bv, a2);
    a3 = fmaf(sA[3][k], bv, a3);
  }
  float bb = bias ? bias[col] : 0.f;
  C[(size_t)(m0 + 0) * N + col] = a0 + bb;
  C[(size_t)(m0 + 1) * N + col] = a1 + bb;
  C[(size_t)(m0 + 2) * N + col] = a2 + bb;
  C[(size_t)(m0 + 3) * N + col] = a3 + bb;
}

// ------------- W_out (J,V) fp32 -> WTf bf16 fragment order -------------
// WTf[bn][ks][nt16][lane][8]; col n = bn*256+nt16*16+(lane&15), j = ks*32+(lane>>4)*8+jj
__global__ void k_wtf(const float* __restrict__ W_out, ushort_t* __restrict__ WTf){
  int bn = blockIdx.x, ks = blockIdx.y;
  int tid = threadIdx.x;
  int lane = tid & 63, nth = tid >> 6;
  int c16 = lane & 15, quad = lane >> 4;
  int j0 = ks * 32 + quad * 8;
#pragma unroll
  for (int i = 0; i < 4; i++){
    int nt16 = nth * 4 + i;
    int n = bn * 256 + nt16 * 16 + c16;
    unsigned int p[4];
#pragma unroll
    for (int h = 0; h < 4; h++){
      unsigned lo = f2bf(W_out[(size_t)(j0 + 2 * h) * cV + n]);
      unsigned hi = f2bf(W_out[(size_t)(j0 + 2 * h + 1) * cV + n]);
      p[h] = lo | (hi << 16);
    }
    uint4 pack; pack.x = p[0]; pack.y = p[1]; pack.z = p[2]; pack.w = p[3];
    *(uint4*)(WTf + (((size_t)(bn * 16 + ks) * 16 + nt16) * 64 + lane) * 8) = pack;
  }
}

// ------------- H fragment-order: Hbf[bm][ks][mg][lane][8] -------------
// row = bm*128 + mg*16 + (lane&15); j = ks*32 + (lane>>4)*8 + jj
// h = tanh(e[b,t,j] + dmatb[b,u,j])   (b_j already folded into dmatb)
__global__ __launch_bounds__(256) void k_hf(const float* __restrict__ e,
                                            const float* __restrict__ dmatb,
                                            ushort_t* __restrict__ Hbf){
  int bm = blockIdx.x;
  int tid = threadIdx.x;
  int lane = tid & 63, mgh = tid >> 6;
  int c16 = lane & 15, quad = lane >> 4;
#pragma unroll
  for (int mgi = 0; mgi < 2; mgi++){
    int mg = mgh + mgi * 4;
    int grow = bm * 128 + mg * 16 + c16;
    int b = grow / cTU;
    int rem = grow % cTU;
    int t = rem / cU1, u = rem % cU1;
    const float* ep = e + (size_t)(b * cT + t) * cJ;
    const float* dp = dmatb + (size_t)(b * cU1 + u) * cJ;
    ushort_t* outp = Hbf + ((size_t)bm * 16 * 8 + mg) * 512 + lane * 8;
#pragma unroll
    for (int ks = 0; ks < 16; ks++){
      int j0 = ks * 32 + quad * 8;
      float4 e0 = *(const float4*)(ep + j0);
      float4 e1 = *(const float4*)(ep + j0 + 4);
      float4 d0 = *(const float4*)(dp + j0);
      float4 d1 = *(const float4*)(dp + j0 + 4);
      unsigned int x0 = (unsigned)f2bf(tanh_fast(e0.x + d0.x)) |
                        ((unsigned)f2bf(tanh_fast(e0.y + d0.y)) << 16);
      unsigned int x1 = (unsigned)f2bf(tanh_fast(e0.z + d0.z)) |
                        ((unsigned)f2bf(tanh_fast(e0.w + d0.w)) << 16);
      unsigned int x2 = (unsigned)f2bf(tanh_fast(e1.x + d1.x)) |
                        ((unsigned)f2bf(tanh_fast(e1.y + d1.y)) << 16);
      unsigned int x3 = (unsigned)f2bf(tanh_fast(e1.z + d1.z)) |
                        ((unsigned)f2bf(tanh_fast(e1.w + d1.w)) << 16);
      uint4 pack; pack.x = x0; pack.y = x1; pack.z = x2; pack.w = x3;
      *(uint4*)(outp + (size_t)ks * 4096) = pack;
    }
  }
}

// ------------- joint GEMM, register-resident, barrier-free K-loop -------------
// grid (4 bn, 520 bm), 256 thr = 4 waves; wave (wm=wid&1, wn=wid>>1) computes
// rows [wm*64,+64) x cols [bn*256+wn*128,+128): 4x8 tiles of mfma 16x16x32 bf16.
// A/B fragments loaded straight from pre-swizzled global (no LDS, no barriers).
__global__ __launch_bounds__(256, 2) void k_joint(
    const ushort_t* __restrict__ Hbf, const ushort_t* __restrict__ WTf,
    const float* __restrict__ b_out, const int* __restrict__ targets,
    float* __restrict__ ps,                       // [4][cM]
    float* __restrict__ blank_g, float* __restrict__ lbl_g)
{
  __shared__ float redS[2][128];
  __shared__ int tgt[128];

  int tid = threadIdx.x;
  int wid = tid >> 6, lane = tid & 63;
  int quad = lane >> 4, c16 = lane & 15;
  int wm = wid & 1, wn = wid >> 1;
  int bn = blockIdx.x, bm = blockIdx.y;
  int rowbase = bm * 128;

  if (tid < 128){
    int grow = rowbase + tid;
    int b = grow / cTU;
    int u = grow % cU1;
    tgt[tid] = (u < cU) ? targets[b * cU + u] : -1;
  }
  __syncthreads();

  f32x4 acc[4][8];
#pragma unroll
  for (int i = 0; i < 4; i++)
#pragma unroll
    for (int j = 0; j < 8; j++)
      acc[i][j] = (f32x4){0.f, 0.f, 0.f, 0.f};

  const ushort_t* aP = Hbf + ((size_t)bm * 16) * 4096 + (wm * 4) * 512 + lane * 8;
  const ushort_t* bP = WTf + ((size_t)bn * 16) * 8192 + (wn * 8) * 512 + lane * 8;

#pragma unroll
  for (int ks = 0; ks < 16; ks++){
    short8 af[4], bf[8];
#pragma unroll
    for (int mt = 0; mt < 4; mt++)
      af[mt] = *(const short8*)(aP + (size_t)ks * 4096 + mt * 512);
#pragma unroll
    for (int nt = 0; nt < 8; nt++)
      bf[nt] = *(const short8*)(bP + (size_t)ks * 8192 + nt * 512);
#pragma unroll
    for (int mt = 0; mt < 4; mt++)
#pragma unroll
      for (int nt = 0; nt < 8; nt++)
        acc[mt][nt] = __builtin_amdgcn_mfma_f32_16x16x32_bf16(af[mt], bf[nt], acc[mt][nt], 0, 0, 0);
  }

  // epilogue: bias, blank/label gather, per-block sum-exp partial (no max; |logit|<~6)
  float bv[8];
#pragma unroll
  for (int nt = 0; nt < 8; nt++) bv[nt] = b_out[bn * 256 + (wn * 8 + nt) * 16 + c16];

#pragma unroll
  for (int mt = 0; mt < 4; mt++){
#pragma unroll
    for (int r = 0; r < 4; r++){
      int rl = wm * 64 + mt * 16 + quad * 4 + r;  // C/D: col=lane&15, row=quad*4+reg (m89)
      float l[8];
#pragma unroll
      for (int nt = 0; nt < 8; nt++) l[nt] = acc[mt][nt][r] + bv[nt];
      if (bn == 0 && wn == 0 && c16 == 0) blank_g[rowbase + rl] = l[0];
      int tg = tgt[rl];
      if (tg >= 0 && (tg >> 8) == bn && ((tg >> 7) & 1) == wn && (tg & 15) == c16){
        int ntw = (tg >> 4) & 7;
        float v = l[0];
#pragma unroll
        for (int k = 1; k < 8; k++) v = (ntw == k) ? l[k] : v;
        lbl_g[rowbase + rl] = v;
      }
      float s = 0.f;
#pragma unroll
      for (int nt = 0; nt < 8; nt++) s += __expf(l[nt]);
      s += __shfl_xor(s, 1, 64);
      s += __shfl_xor(s, 2, 64);
      s += __shfl_xor(s, 4, 64);
      s += __shfl_xor(s, 8, 64);
      if (c16 == 0) redS[wn][rl] = s;
    }
  }
  __syncthreads();
  if (tid < 128)
    ps[(size_t)bn * cM + rowbase + tid] = redS[0][tid] + redS[1][tid];
}

// ------------- RNN-T alpha DP (lse merge fused into staging) -------------
__global__ __launch_bounds__(256) void k_dp(
    const float* __restrict__ blank_g, const float* __restrict__ lbl_g,
    const float* __restrict__ ps,
    const int* __restrict__ in_len, const int* __restrict__ tgt_len,
    float* __restrict__ afin)
{
  __shared__ float sbb[cTU];   // 65 KB
  __shared__ float slb[cTU];   // 65 KB
  int b = blockIdx.x;
  for (int i = threadIdx.x; i < cTU; i += 256){
    int grow = b * cTU + i;
    float S = ps[grow] + ps[(size_t)cM + grow] + ps[(size_t)2 * cM + grow] + ps[(size_t)3 * cM + grow];
    float lse = __logf(S);
    sbb[i] = blank_g[grow] - lse;
    slb[i] = ((i % cU1) < cU) ? (lbl_g[grow] - lse) : NEGF;
  }
  __syncthreads();
  if (threadIdx.x >= 64) return;

  int u = threadIdx.x;                 // 0..63
  int til = in_len[b] - 1;
  int tl  = tgt_len[b];                // 32..64
  float Dprev = (u == 0) ? 0.f : NEGF; // D_d[u] = alpha[d-u][u]
  float D64prev = NEGF;
  bool cap64 = (tl == 64);

  for (int d = 1; d <= 319; d++){
    int t = d - u;
    bool tv  = (t >= 0) & (t <= cT - 1);
    bool t1v = (t >= 1) & (t <= cT - 1);
    float blv = t1v ? sbb[(t - 1) * cU1 + u] : NEGF;
    float lvv = (u >= 1 && tv && (u - 1) < tl) ? slb[t * cU1 + (u - 1)] : NEGF;
    float up = __shfl_up(Dprev, 1, 64);
    float term1 = t1v ? (Dprev + blv) : NEGF;
    float term2 = (u >= 1 && tv) ? (up + lvv) : NEGF;
    float Dcur = tv ? logadd(term1, term2) : NEGF;
    if (u == tl && t == til)
      afin[b] = Dcur + sbb[til * cU1 + u];
    if (cap64){
      int t64 = d - 64;
      if (t64 >= 0 && t64 <= cT - 1){
        float s63 = __shfl(Dprev, 63, 64);
        float b64v = (t64 >= 1) ? sbb[(t64 - 1) * cU1 + 64] : NEGF;
        float tA = (t64 >= 1) ? (D64prev + b64v) : NEGF;
        float tB = s63 + slb[t64 * cU1 + 63];
        float D64 = logadd(tA, tB);
        if (t64 == til && u == 0)
          afin[b] = D64 + sbb[til * cU1 + 64];
        D64prev = D64;
      }
    }
    Dprev = Dcur;
  }
}

__global__ void k_final(const float* __restrict__ afin, float* __restrict__ out){
  if (threadIdx.x == 0)
    out[0] = -0.25f * (afin[0] + afin[1] + afin[2] + afin[3]);
}

extern "C" void kernel_launch(void* const* d_in, const int* in_sizes, int n_in,
                              void* d_out, int out_size, void* d_ws, size_t ws_size,
                              hipStream_t stream)
{
  (void)in_sizes; (void)n_in; (void)out_size; (void)ws_size;
  const float* inputs = (const float*)d_in[0];   // (4,256,80)
  const float* W_enc  = (const float*)d_in[1];   // (80,512)
  const float* emb    = (const float*)d_in[2];   // (1024,512)
  const float* W_jenc = (const float*)d_in[3];   // (512,512)
  const float* W_jdec = (const float*)d_in[4];   // (512,512)
  const float* b_j    = (const float*)d_in[5];   // (512)
  const float* W_out  = (const float*)d_in[6];   // (512,1024)
  const float* b_out  = (const float*)d_in[7];   // (1024)
  const int* targets  = (const int*)d_in[8];     // (4,64)
  const int* in_len   = (const int*)d_in[9];     // (4)
  const int* tgt_len  = (const int*)d_in[10];    // (4)

  char* w = (char*)d_ws;
  auto alloc = [&](size_t bytes){ char* p = w; w += (bytes + 255) & ~(size_t)255; return p; };
  float* Wcomb   = (float*)alloc((size_t)80 * 512 * 4);
  float* e       = (float*)alloc((size_t)1024 * 512 * 4);
  float* dec     = (float*)alloc((size_t)260 * 512 * 4);
  float* dmatb   = (float*)alloc((size_t)260 * 512 * 4);
  float* blank_g = (float*)alloc((size_t)cM * 4);
  float* lbl_g   = (float*)alloc((size_t)cM * 4);
  float* ps      = (float*)alloc((size_t)4 * cM * 4);
  float* afin    = (float*)alloc(256);
  ushort_t* Hbf  = (ushort_t*)alloc((size_t)cM * 512 * 2);
  ushort_t* WTf  = (ushort_t*)alloc((size_t)1024 * 512 * 2);

  // e = inputs @ (W_enc @ W_jenc)   (associativity: K=80 GEMM instead of K=512)
  k_gemm4<512><<<dim3(2, 20),  256, 0, stream>>>(W_enc, W_jenc, Wcomb, 512, nullptr);
  k_gather_dec<<<260, 128, 0, stream>>>(emb, targets, dec);
  k_gemm4<80> <<<dim3(2, 256), 256, 0, stream>>>(inputs, Wcomb, e, 512, nullptr);
  k_gemm4<512><<<dim3(2, 65),  256, 0, stream>>>(dec, W_jdec, dmatb, 512, b_j);
  k_wtf<<<dim3(4, 16), 256, 0, stream>>>(W_out, WTf);
  k_hf<<<520, 256, 0, stream>>>(e, dmatb, Hbf);
  k_joint<<<dim3(4, 520), 256, 0, stream>>>(Hbf, WTf, b_out, targets, ps, blank_g, lbl_g);
  k_dp<<<4, 256, 0, stream>>>(blank_g, lbl_g, ps, in_len, tgt_len, afin);
  k_final<<<1, 64, 0, stream>>>(afin, (float*)d_out);
}

// Round 4
// 374.052 us; speedup vs baseline: 1.2979x; 1.0228x over previous
//
#include <hip/hip_runtime.h>
#include <stdint.h>

#define NEGF (-1e30f)

typedef unsigned short ushort_t;
typedef __attribute__((ext_vector_type(8))) short short8;
typedef __attribute__((ext_vector_type(4))) float f32x4;

constexpr int cB = 4, cT = 256, cU = 64, cU1 = 65, cV = 1024, cF = 80, cH = 512, cJ = 512;
constexpr int cM = cB * cT * cU1; // 66560 = 128 * 520 (t-minor order: m=(b*65+u)*256+t)
constexpr int cTU = cT * cU1;     // 16640

__device__ __forceinline__ unsigned short f2bf(float x){
  union { float f; unsigned int u; } c; c.f = x;
  unsigned int r = c.u + 0x7FFFu + ((c.u >> 16) & 1u);
  return (unsigned short)(r >> 16);
}

__device__ __forceinline__ float tanh_fast(float x){
  x = fminf(15.f, fmaxf(-15.f, x));
  float e = __expf(2.f * x);
  return (e - 1.f) / (e + 1.f);
}

__device__ __forceinline__ float logadd(float x, float y){
  float m = fmaxf(x, y);
  return m + __logf(1.f + __expf(-fabsf(x - y)));
}

// ------------- small fp32 GEMM: C[M,N] = A[M,K] @ B[K,N], 4 rows/block -------------
template<int K>
__global__ void k_gemm4(const float* __restrict__ A, const float* __restrict__ Bm,
                        float* __restrict__ C, int N){
  __shared__ float sA[4][K];
  int m0 = blockIdx.y * 4;
  int col = blockIdx.x * 256 + threadIdx.x;
  for (int i = threadIdx.x; i < 4 * K; i += 256)
    sA[i / K][i % K] = A[(size_t)(m0 + i / K) * K + (i % K)];
  __syncthreads();
  float a0 = 0.f, a1 = 0.f, a2 = 0.f, a3 = 0.f;
#pragma unroll 8
  for (int k = 0; k < K; k++){
    float bv = Bm[(size_t)k * N + col];
    a0 = fmaf(sA[0][k], bv, a0);
    a1 = fmaf(sA[1][k], bv, a1);
    a2 = fmaf(sA[2][k], bv, a2);
    a3 = fmaf(sA[3][k], bv, a3);
  }
  C[(size_t)(m0 + 0) * N + col] = a0;
  C[(size_t)(m0 + 1) * N + col] = a1;
  C[(size_t)(m0 + 2) * N + col] = a2;
  C[(size_t)(m0 + 3) * N + col] = a3;
}

// ------------- dmatb = emb[padded] @ W_jdec + b_j  (gather fused into A-staging) -------------
__global__ void k_gemm_dec(const float* __restrict__ emb, const int* __restrict__ targets,
                           const float* __restrict__ W_jdec, const float* __restrict__ b_j,
                           float* __restrict__ dmatb){
  __shared__ float sA[4][512];
  int m0 = blockIdx.y * 4;            // 260 rows / 4 = 65 blocks
  int col = blockIdx.x * 256 + threadIdx.x;
  for (int i = threadIdx.x; i < 4 * 512; i += 256){
    int r = i >> 9, c = i & 511;
    int row = m0 + r;
    int b = row / cU1, u = row % cU1;
    int src = (u == 0) ? 0 : targets[b * cU + (u - 1)];
    sA[r][c] = emb[(size_t)src * cH + c];
  }
  __syncthreads();
  float a0 = 0.f, a1 = 0.f, a2 = 0.f, a3 = 0.f;
#pragma unroll 8
  for (int k = 0; k < 512; k++){
    float bv = W_jdec[(size_t)k * cJ + col];
    a0 = fmaf(sA[0][k], bv, a0);
    a1 = fmaf(sA[1][k], bv, a1);
    a2 = fmaf(sA[2][k], bv, a2);
    a3 = fmaf(sA[3][k], bv, a3);
  }
  float bb = b_j[col];
  dmatb[(size_t)(m0 + 0) * cJ + col] = a0 + bb;
  dmatb[(size_t)(m0 + 1) * cJ + col] = a1 + bb;
  dmatb[(size_t)(m0 + 2) * cJ + col] = a2 + bb;
  dmatb[(size_t)(m0 + 3) * cJ + col] = a3 + bb;
}

// ------------- W_out (J,V) fp32 -> WTf bf16 fragment order -------------
// WTf[bn][ks][nt16][lane][8]; col n = bn*256+nt16*16+(lane&15), j = ks*32+(lane>>4)*8+jj
__global__ void k_wtf(const float* __restrict__ W_out, ushort_t* __restrict__ WTf){
  int bn = blockIdx.x, ks = blockIdx.y;
  int tid = threadIdx.x;
  int lane = tid & 63, nth = tid >> 6;
  int c16 = lane & 15, quad = lane >> 4;
  int j0 = ks * 32 + quad * 8;
#pragma unroll
  for (int i = 0; i < 4; i++){
    int nt16 = nth * 4 + i;
    int n = bn * 256 + nt16 * 16 + c16;
    unsigned int p[4];
#pragma unroll
    for (int h = 0; h < 4; h++){
      unsigned lo = f2bf(W_out[(size_t)(j0 + 2 * h) * cV + n]);
      unsigned hi = f2bf(W_out[(size_t)(j0 + 2 * h + 1) * cV + n]);
      p[h] = lo | (hi << 16);
    }
    uint4 pack; pack.x = p[0]; pack.y = p[1]; pack.z = p[2]; pack.w = p[3];
    *(uint4*)(WTf + (((size_t)(bn * 16 + ks) * 16 + nt16) * 64 + lane) * 8) = pack;
  }
}

// ------------- H fragment-order, t-minor, coalesced via LDS bounce -------------
// block bm (520): bu=bm>>1 fixed (b,u), rows t = (bm&1)*128 .. +128.
// Hbf[bm][ks][mg][lane][8]: row = mg*16+(lane&15) [local t], j = ks*32+(lane>>4)*8+jj
__global__ __launch_bounds__(256) void k_hf(const float* __restrict__ e,
                                            const float* __restrict__ dmatb,
                                            ushort_t* __restrict__ Hbf){
  __shared__ ushort_t sH[16 * 520];   // 16 rows x 512 j, pad 8 -> bank stride 4 (2-way, free)
  int tid = threadIdx.x;
  int wid = tid >> 6, lane = tid & 63;
  int c16 = lane & 15, quad = lane >> 4;
  int bm = blockIdx.x;
  int bu = bm >> 1, thalf = bm & 1;
  int b = bu / cU1;
  int t0 = thalf * 128;

  // d-row (b_j folded) for this block's fixed u: 8 values per lane (j = lane*8..)
  float dj[8];
  const float4* dp = (const float4*)(dmatb + (size_t)bu * cJ + lane * 8);
  float4 dA = dp[0], dB = dp[1];
  dj[0] = dA.x; dj[1] = dA.y; dj[2] = dA.z; dj[3] = dA.w;
  dj[4] = dB.x; dj[5] = dB.y; dj[6] = dB.z; dj[7] = dB.w;

  const float* erow0 = e + ((size_t)(b * cT + t0)) * cJ + lane * 8;
  ushort_t* outb = Hbf + (size_t)bm * 65536 + lane * 8;

  for (int mg = 0; mg < 8; mg++){
    // compute 16 rows (wave wid handles rows wid*4..+4), coalesced e reads
#pragma unroll
    for (int rr = 0; rr < 4; rr++){
      int rloc = wid * 4 + rr;
      const float* ep = erow0 + ((size_t)(mg * 16 + rloc)) * cJ;
      float4 e0 = *(const float4*)ep;
      float4 e1 = *(const float4*)(ep + 4);
      unsigned int x0 = (unsigned)f2bf(tanh_fast(e0.x + dj[0])) |
                        ((unsigned)f2bf(tanh_fast(e0.y + dj[1])) << 16);
      unsigned int x1 = (unsigned)f2bf(tanh_fast(e0.z + dj[2])) |
                        ((unsigned)f2bf(tanh_fast(e0.w + dj[3])) << 16);
      unsigned int x2 = (unsigned)f2bf(tanh_fast(e1.x + dj[4])) |
                        ((unsigned)f2bf(tanh_fast(e1.y + dj[5])) << 16);
      unsigned int x3 = (unsigned)f2bf(tanh_fast(e1.z + dj[6])) |
                        ((unsigned)f2bf(tanh_fast(e1.w + dj[7])) << 16);
      uint4 pack; pack.x = x0; pack.y = x1; pack.z = x2; pack.w = x3;
      *(uint4*)(sH + rloc * 520 + lane * 8) = pack;
    }
    __syncthreads();
    // read fragments (2-way bank alias), store coalesced
#pragma unroll
    for (int q = 0; q < 4; q++){
      int ks = wid * 4 + q;
      uint4 v = *(const uint4*)(sH + c16 * 520 + ks * 32 + quad * 8);
      *(uint4*)(outb + (size_t)ks * 4096 + mg * 512) = v;
    }
    __syncthreads();
  }
}

// ------------- joint GEMM, register-resident, barrier-free K-loop -------------
// 1-D grid 2080: bm=(bid>>5)*8+(bid&7), bn=(bid>>3)&3 — the 4 bn of one bm land on
// the same XCD (delta-8 bids) AND adjacent dispatch slots (co-resident) -> Hbf via L2.
// 256 thr = 4 waves; wave (wm=wid&1, wn=wid>>1): rows [wm*64,+64) x cols [bn*256+wn*128,+128).
__global__ __launch_bounds__(256, 2) void k_joint(
    const ushort_t* __restrict__ Hbf, const ushort_t* __restrict__ WTf,
    const float* __restrict__ b_out, const int* __restrict__ targets,
    float* __restrict__ ps,                       // [4][cM], (t,u)-linear index
    float* __restrict__ blank_g, float* __restrict__ lbl_g)
{
  __shared__ float redS[2][128];

  int tid = threadIdx.x;
  int wid = tid >> 6, lane = tid & 63;
  int quad = lane >> 4, c16 = lane & 15;
  int wm = wid & 1, wn = wid >> 1;
  int bid = blockIdx.x;
  int bm = ((bid >> 5) << 3) + (bid & 7);
  int bn = (bid >> 3) & 3;
  int bu = bm >> 1, thalf = bm & 1;
  int b = bu / cU1, u = bu - b * cU1;
  int tg = (u < cU) ? targets[b * cU + u] : -1;
  int lin0 = (b * cT + thalf * 128) * cU1 + u;   // (t,u)-linear base; + rl*65 per local row

  f32x4 acc[4][8];
#pragma unroll
  for (int i = 0; i < 4; i++)
#pragma unroll
    for (int j = 0; j < 8; j++)
      acc[i][j] = (f32x4){0.f, 0.f, 0.f, 0.f};

  const ushort_t* aP = Hbf + ((size_t)bm * 16) * 4096 + (wm * 4) * 512 + lane * 8;
  const ushort_t* bP = WTf + ((size_t)bn * 16) * 8192 + (wn * 8) * 512 + lane * 8;

#pragma unroll
  for (int ks = 0; ks < 16; ks++){
    short8 af[4], bf[8];
#pragma unroll
    for (int mt = 0; mt < 4; mt++)
      af[mt] = *(const short8*)(aP + (size_t)ks * 4096 + mt * 512);
#pragma unroll
    for (int nt = 0; nt < 8; nt++)
      bf[nt] = *(const short8*)(bP + (size_t)ks * 8192 + nt * 512);
#pragma unroll
    for (int mt = 0; mt < 4; mt++)
#pragma unroll
      for (int nt = 0; nt < 8; nt++)
        acc[mt][nt] = __builtin_amdgcn_mfma_f32_16x16x32_bf16(af[mt], bf[nt], acc[mt][nt], 0, 0, 0);
  }

  // epilogue: bias, blank/label gather (scalar target per block), sum-exp partial
  float bv[8];
#pragma unroll
  for (int nt = 0; nt < 8; nt++) bv[nt] = b_out[bn * 256 + (wn * 8 + nt) * 16 + c16];

  bool ownL = (tg >= 0) && ((tg >> 8) == bn) && ((((tg >> 4) & 15) >> 3) == wn);
  int ntO = (tg >> 4) & 7;
  int tgc = tg & 15;

#pragma unroll
  for (int mt = 0; mt < 4; mt++){
#pragma unroll
    for (int r = 0; r < 4; r++){
      int rl = wm * 64 + mt * 16 + quad * 4 + r;  // C/D: col=lane&15, row=quad*4+reg (m89)
      float l[8];
#pragma unroll
      for (int nt = 0; nt < 8; nt++) l[nt] = acc[mt][nt][r] + bv[nt];
      if (bn == 0 && wn == 0 && c16 == 0) blank_g[lin0 + rl * cU1] = l[0];
      if (ownL && c16 == tgc){
        float v = l[0];
#pragma unroll
        for (int k = 1; k < 8; k++) v = (ntO == k) ? l[k] : v;
        lbl_g[lin0 + rl * cU1] = v;
      }
      float s = 0.f;
#pragma unroll
      for (int nt = 0; nt < 8; nt++) s += __expf(l[nt]);
      s += __shfl_xor(s, 1, 64);
      s += __shfl_xor(s, 2, 64);
      s += __shfl_xor(s, 4, 64);
      s += __shfl_xor(s, 8, 64);
      if (c16 == 0) redS[wn][rl] = s;
    }
  }
  __syncthreads();
  if (tid < 128)
    ps[(size_t)bn * cM + lin0 + tid * cU1] = redS[0][tid] + redS[1][tid];
}

// ------------- RNN-T alpha DP (lse merge fused into staging) -------------
__global__ __launch_bounds__(256) void k_dp(
    const float* __restrict__ blank_g, const float* __restrict__ lbl_g,
    const float* __restrict__ ps,
    const int* __restrict__ in_len, const int* __restrict__ tgt_len,
    float* __restrict__ afin)
{
  __shared__ float sbb[cTU];   // 65 KB, (t,u)-linear
  __shared__ float slb[cTU];   // 65 KB
  int b = blockIdx.x;
  for (int i = threadIdx.x; i < cTU; i += 256){
    int grow = b * cTU + i;
    float S = ps[grow] + ps[(size_t)cM + grow] + ps[(size_t)2 * cM + grow] + ps[(size_t)3 * cM + grow];
    float lse = __logf(S);
    sbb[i] = blank_g[grow] - lse;
    slb[i] = ((i % cU1) < cU) ? (lbl_g[grow] - lse) : NEGF;
  }
  __syncthreads();
  if (threadIdx.x >= 64) return;

  int u = threadIdx.x;                 // 0..63
  int til = in_len[b] - 1;
  int tl  = tgt_len[b];                // 32..64
  float Dprev = (u == 0) ? 0.f : NEGF; // D_d[u] = alpha[d-u][u]
  float D64prev = NEGF;
  bool cap64 = (tl == 64);

  for (int d = 1; d <= 319; d++){
    int t = d - u;
    bool tv  = (t >= 0) & (t <= cT - 1);
    bool t1v = (t >= 1) & (t <= cT - 1);
    float blv = t1v ? sbb[(t - 1) * cU1 + u] : NEGF;
    float lvv = (u >= 1 && tv && (u - 1) < tl) ? slb[t * cU1 + (u - 1)] : NEGF;
    float up = __shfl_up(Dprev, 1, 64);
    float term1 = t1v ? (Dprev + blv) : NEGF;
    float term2 = (u >= 1 && tv) ? (up + lvv) : NEGF;
    float Dcur = tv ? logadd(term1, term2) : NEGF;
    if (u == tl && t == til)
      afin[b] = Dcur + sbb[til * cU1 + u];
    if (cap64){
      int t64 = d - 64;
      if (t64 >= 0 && t64 <= cT - 1){
        float s63 = __shfl(Dprev, 63, 64);
        float b64v = (t64 >= 1) ? sbb[(t64 - 1) * cU1 + 64] : NEGF;
        float tA = (t64 >= 1) ? (D64prev + b64v) : NEGF;
        float tB = s63 + slb[t64 * cU1 + 63];
        float D64 = logadd(tA, tB);
        if (t64 == til && u == 0)
          afin[b] = D64 + sbb[til * cU1 + 64];
        D64prev = D64;
      }
    }
    Dprev = Dcur;
  }
}

__global__ void k_final(const float* __restrict__ afin, float* __restrict__ out){
  if (threadIdx.x == 0)
    out[0] = -0.25f * (afin[0] + afin[1] + afin[2] + afin[3]);
}

extern "C" void kernel_launch(void* const* d_in, const int* in_sizes, int n_in,
                              void* d_out, int out_size, void* d_ws, size_t ws_size,
                              hipStream_t stream)
{
  (void)in_sizes; (void)n_in; (void)out_size; (void)ws_size;
  const float* inputs = (const float*)d_in[0];   // (4,256,80)
  const float* W_enc  = (const float*)d_in[1];   // (80,512)
  const float* emb    = (const float*)d_in[2];   // (1024,512)
  const float* W_jenc = (const float*)d_in[3];   // (512,512)
  const float* W_jdec = (const float*)d_in[4];   // (512,512)
  const float* b_j    = (const float*)d_in[5];   // (512)
  const float* W_out  = (const float*)d_in[6];   // (512,1024)
  const float* b_out  = (const float*)d_in[7];   // (1024)
  const int* targets  = (const int*)d_in[8];     // (4,64)
  const int* in_len   = (const int*)d_in[9];     // (4)
  const int* tgt_len  = (const int*)d_in[10];    // (4)

  char* w = (char*)d_ws;
  auto alloc = [&](size_t bytes){ char* p = w; w += (bytes + 255) & ~(size_t)255; return p; };
  float* Wcomb   = (float*)alloc((size_t)80 * 512 * 4);
  float* e       = (float*)alloc((size_t)1024 * 512 * 4);
  float* dmatb   = (float*)alloc((size_t)260 * 512 * 4);
  float* blank_g = (float*)alloc((size_t)cM * 4);
  float* lbl_g   = (float*)alloc((size_t)cM * 4);
  float* ps      = (float*)alloc((size_t)4 * cM * 4);
  float* afin    = (float*)alloc(256);
  ushort_t* Hbf  = (ushort_t*)alloc((size_t)cM * 512 * 2);
  ushort_t* WTf  = (ushort_t*)alloc((size_t)1024 * 512 * 2);

  // e = inputs @ (W_enc @ W_jenc)   (associativity: K=80 GEMM instead of K=512)
  k_gemm4<512><<<dim3(2, 20),  256, 0, stream>>>(W_enc, W_jenc, Wcomb, 512);
  k_gemm4<80> <<<dim3(2, 256), 256, 0, stream>>>(inputs, Wcomb, e, 512);
  k_gemm_dec<<<dim3(2, 65), 256, 0, stream>>>(emb, targets, W_jdec, b_j, dmatb);
  k_wtf<<<dim3(4, 16), 256, 0, stream>>>(W_out, WTf);
  k_hf<<<520, 256, 0, stream>>>(e, dmatb, Hbf);
  k_joint<<<2080, 256, 0, stream>>>(Hbf, WTf, b_out, targets, ps, blank_g, lbl_g);
  k_dp<<<4, 256, 0, stream>>>(blank_g, lbl_g, ps, in_len, tgt_len, afin);
  k_final<<<1, 64, 0, stream>>>(afin, (float*)d_out);
}

// Round 5
// 305.542 us; speedup vs baseline: 1.5889x; 1.2242x over previous
//
#include <hip/hip_runtime.h>
#include <stdint.h>

#define NEGF (-1e30f)

typedef unsigned short ushort_t;
typedef __attribute__((ext_vector_type(8))) short short8;
typedef __attribute__((ext_vector_type(4))) float f32x4;

constexpr int cB = 4, cT = 256, cU = 64, cU1 = 65, cV = 1024, cF = 80, cH = 512, cJ = 512;
constexpr int cM = cB * cT * cU1; // 66560
constexpr int cTU = cT * cU1;     // 16640 (per-batch (u,t) plane: u*256+t)

__device__ __forceinline__ unsigned short f2bf(float x){
  union { float f; unsigned int u; } c; c.f = x;
  unsigned int r = c.u + 0x7FFFu + ((c.u >> 16) & 1u);
  return (unsigned short)(r >> 16);
}

__device__ __forceinline__ float tanh_fast(float x){
  x = fminf(15.f, fmaxf(-15.f, x));
  float e = __expf(2.f * x);
  return (e - 1.f) / (e + 1.f);
}

__device__ __forceinline__ float logadd(float x, float y){
  float m = fmaxf(x, y);
  return m + __logf(1.f + __expf(-fabsf(x - y)));
}

// ------------- fused prologue: 3 independent jobs in one dispatch -------------
// bid 0..39   : Wcomb(80,512)  = W_enc @ W_jenc            (grid was 2x20)
// bid 40..169 : dmatb(260,512) = emb[padded] @ W_jdec + b_j (grid was 2x65)
// bid 170..233: WTf bf16 fragment-order transpose of W_out  (grid was 4x16)
__global__ __launch_bounds__(256) void k_pre(
    const float* __restrict__ W_enc, const float* __restrict__ W_jenc,
    float* __restrict__ Wcomb,
    const float* __restrict__ emb, const int* __restrict__ targets,
    const float* __restrict__ W_jdec, const float* __restrict__ b_j,
    float* __restrict__ dmatb,
    const float* __restrict__ W_out, ushort_t* __restrict__ WTf)
{
  __shared__ float sA[4][512];
  int bid = blockIdx.x;
  int tid = threadIdx.x;

  if (bid < 170){
    // -------- one of the two K=512 fp32 GEMMs --------
    bool isW = (bid < 40);
    int id = isW ? bid : bid - 40;
    int bx = id & 1, by = id >> 1;
    int m0 = by * 4;
    int col = bx * 256 + tid;
    const float* Bm = isW ? W_jenc : W_jdec;
    for (int i = tid; i < 4 * 512; i += 256){
      int r = i >> 9, c = i & 511;
      if (isW){
        sA[r][c] = W_enc[(size_t)(m0 + r) * 512 + c];
      } else {
        int row = m0 + r;
        int b = row / cU1, u = row % cU1;
        int src = (u == 0) ? 0 : targets[b * cU + (u - 1)];
        sA[r][c] = emb[(size_t)src * cH + c];
      }
    }
    __syncthreads();
    float a0 = 0.f, a1 = 0.f, a2 = 0.f, a3 = 0.f;
#pragma unroll 8
    for (int k = 0; k < 512; k++){
      float bv = Bm[(size_t)k * cJ + col];
      a0 = fmaf(sA[0][k], bv, a0);
      a1 = fmaf(sA[1][k], bv, a1);
      a2 = fmaf(sA[2][k], bv, a2);
      a3 = fmaf(sA[3][k], bv, a3);
    }
    float bb = isW ? 0.f : b_j[col];
    float* C = isW ? Wcomb : dmatb;
    C[(size_t)(m0 + 0) * cJ + col] = a0 + bb;
    C[(size_t)(m0 + 1) * cJ + col] = a1 + bb;
    C[(size_t)(m0 + 2) * cJ + col] = a2 + bb;
    C[(size_t)(m0 + 3) * cJ + col] = a3 + bb;
  } else {
    // -------- W_out (J,V) -> WTf[bn][ks][nt16][lane][8] bf16 --------
    int id = bid - 170;
    int bn = id & 3, ks = id >> 2;
    int lane = tid & 63, nth = tid >> 6;
    int c16 = lane & 15, quad = lane >> 4;
    int j0 = ks * 32 + quad * 8;
#pragma unroll
    for (int i = 0; i < 4; i++){
      int nt16 = nth * 4 + i;
      int n = bn * 256 + nt16 * 16 + c16;
      unsigned int p[4];
#pragma unroll
      for (int h = 0; h < 4; h++){
        unsigned lo = f2bf(W_out[(size_t)(j0 + 2 * h) * cV + n]);
        unsigned hi = f2bf(W_out[(size_t)(j0 + 2 * h + 1) * cV + n]);
        p[h] = lo | (hi << 16);
      }
      uint4 pack; pack.x = p[0]; pack.y = p[1]; pack.z = p[2]; pack.w = p[3];
      *(uint4*)(WTf + (((size_t)(bn * 16 + ks) * 16 + nt16) * 64 + lane) * 8) = pack;
    }
  }
}

// ------------- e = inputs @ Wcomb  (K=80), 4 rows/block -------------
__global__ void k_gemm_e(const float* __restrict__ A, const float* __restrict__ Bm,
                         float* __restrict__ C){
  __shared__ float sA[4][80];
  int m0 = blockIdx.y * 4;
  int col = blockIdx.x * 256 + threadIdx.x;
  for (int i = threadIdx.x; i < 4 * 80; i += 256)
    sA[i / 80][i % 80] = A[(size_t)(m0 + i / 80) * 80 + (i % 80)];
  __syncthreads();
  float a0 = 0.f, a1 = 0.f, a2 = 0.f, a3 = 0.f;
#pragma unroll 8
  for (int k = 0; k < 80; k++){
    float bv = Bm[(size_t)k * cJ + col];
    a0 = fmaf(sA[0][k], bv, a0);
    a1 = fmaf(sA[1][k], bv, a1);
    a2 = fmaf(sA[2][k], bv, a2);
    a3 = fmaf(sA[3][k], bv, a3);
  }
  C[(size_t)(m0 + 0) * cJ + col] = a0;
  C[(size_t)(m0 + 1) * cJ + col] = a1;
  C[(size_t)(m0 + 2) * cJ + col] = a2;
  C[(size_t)(m0 + 3) * cJ + col] = a3;
}

// ------------- H fragment-order, t-minor, coalesced via LDS bounce -------------
// block bm (520): bu=bm>>1 fixed (b,u), rows t = (bm&1)*128 .. +128.
// Hbf[bm][ks][mg][lane][8]: row = mg*16+(lane&15) [local t], j = ks*32+(lane>>4)*8+jj
__global__ __launch_bounds__(256) void k_hf(const float* __restrict__ e,
                                            const float* __restrict__ dmatb,
                                            ushort_t* __restrict__ Hbf){
  __shared__ ushort_t sH[16 * 520];   // pad 8 -> bank stride 4 (2-way, free)
  int tid = threadIdx.x;
  int wid = tid >> 6, lane = tid & 63;
  int c16 = lane & 15, quad = lane >> 4;
  int bm = blockIdx.x;
  int bu = bm >> 1, thalf = bm & 1;
  int b = bu / cU1;
  int t0 = thalf * 128;

  float dj[8];
  const float4* dp = (const float4*)(dmatb + (size_t)bu * cJ + lane * 8);
  float4 dA = dp[0], dB = dp[1];
  dj[0] = dA.x; dj[1] = dA.y; dj[2] = dA.z; dj[3] = dA.w;
  dj[4] = dB.x; dj[5] = dB.y; dj[6] = dB.z; dj[7] = dB.w;

  const float* erow0 = e + ((size_t)(b * cT + t0)) * cJ + lane * 8;
  ushort_t* outb = Hbf + (size_t)bm * 65536 + lane * 8;

  for (int mg = 0; mg < 8; mg++){
#pragma unroll
    for (int rr = 0; rr < 4; rr++){
      int rloc = wid * 4 + rr;
      const float* ep = erow0 + ((size_t)(mg * 16 + rloc)) * cJ;
      float4 e0 = *(const float4*)ep;
      float4 e1 = *(const float4*)(ep + 4);
      unsigned int x0 = (unsigned)f2bf(tanh_fast(e0.x + dj[0])) |
                        ((unsigned)f2bf(tanh_fast(e0.y + dj[1])) << 16);
      unsigned int x1 = (unsigned)f2bf(tanh_fast(e0.z + dj[2])) |
                        ((unsigned)f2bf(tanh_fast(e0.w + dj[3])) << 16);
      unsigned int x2 = (unsigned)f2bf(tanh_fast(e1.x + dj[4])) |
                        ((unsigned)f2bf(tanh_fast(e1.y + dj[5])) << 16);
      unsigned int x3 = (unsigned)f2bf(tanh_fast(e1.z + dj[6])) |
                        ((unsigned)f2bf(tanh_fast(e1.w + dj[7])) << 16);
      uint4 pack; pack.x = x0; pack.y = x1; pack.z = x2; pack.w = x3;
      *(uint4*)(sH + rloc * 520 + lane * 8) = pack;
    }
    __syncthreads();
#pragma unroll
    for (int q = 0; q < 4; q++){
      int ks = wid * 4 + q;
      uint4 v = *(const uint4*)(sH + c16 * 520 + ks * 32 + quad * 8);
      *(uint4*)(outb + (size_t)ks * 4096 + mg * 512) = v;
    }
    __syncthreads();
  }
}

// ------------- joint GEMM, register-resident, barrier-free K-loop -------------
// 1-D grid 2080: bm=(bid>>5)*8+(bid&7), bn=(bid>>3)&3 — the 4 bn of one bm share an
// XCD (delta-8 bids) and adjacent dispatch slots -> Hbf refetch served by L2.
// Output layout is (b, u, t): lin0 = (b*65+u)*256 + t  (coalesced stores; DP-friendly).
__global__ __launch_bounds__(256, 2) void k_joint(
    const ushort_t* __restrict__ Hbf, const ushort_t* __restrict__ WTf,
    const float* __restrict__ b_out, const int* __restrict__ targets,
    float* __restrict__ ps,                       // [4][cM]
    float* __restrict__ blank_g, float* __restrict__ lbl_g)
{
  __shared__ float redS[2][128];

  int tid = threadIdx.x;
  int wid = tid >> 6, lane = tid & 63;
  int quad = lane >> 4, c16 = lane & 15;
  int wm = wid & 1, wn = wid >> 1;
  int bid = blockIdx.x;
  int bm = ((bid >> 5) << 3) + (bid & 7);
  int bn = (bid >> 3) & 3;
  int bu = bm >> 1, thalf = bm & 1;
  int b = bu / cU1, u = bu - b * cU1;
  int tg = (u < cU) ? targets[b * cU + u] : -1;
  int lin0 = bu * cT + thalf * 128;    // (b,u,t)-linear base; + rl per local row

  f32x4 acc[4][8];
#pragma unroll
  for (int i = 0; i < 4; i++)
#pragma unroll
    for (int j = 0; j < 8; j++)
      acc[i][j] = (f32x4){0.f, 0.f, 0.f, 0.f};

  const ushort_t* aP = Hbf + ((size_t)bm * 16) * 4096 + (wm * 4) * 512 + lane * 8;
  const ushort_t* bP = WTf + ((size_t)bn * 16) * 8192 + (wn * 8) * 512 + lane * 8;

#pragma unroll
  for (int ks = 0; ks < 16; ks++){
    short8 af[4], bf[8];
#pragma unroll
    for (int mt = 0; mt < 4; mt++)
      af[mt] = *(const short8*)(aP + (size_t)ks * 4096 + mt * 512);
#pragma unroll
    for (int nt = 0; nt < 8; nt++)
      bf[nt] = *(const short8*)(bP + (size_t)ks * 8192 + nt * 512);
#pragma unroll
    for (int mt = 0; mt < 4; mt++)
#pragma unroll
      for (int nt = 0; nt < 8; nt++)
        acc[mt][nt] = __builtin_amdgcn_mfma_f32_16x16x32_bf16(af[mt], bf[nt], acc[mt][nt], 0, 0, 0);
  }

  float bv[8];
#pragma unroll
  for (int nt = 0; nt < 8; nt++) bv[nt] = b_out[bn * 256 + (wn * 8 + nt) * 16 + c16];

  bool ownL = (tg >= 0) && ((tg >> 8) == bn) && ((((tg >> 4) & 15) >> 3) == wn);
  int ntO = (tg >> 4) & 7;
  int tgc = tg & 15;

#pragma unroll
  for (int mt = 0; mt < 4; mt++){
#pragma unroll
    for (int r = 0; r < 4; r++){
      int rl = wm * 64 + mt * 16 + quad * 4 + r;  // C/D: col=lane&15, row=quad*4+reg (m89)
      float l[8];
#pragma unroll
      for (int nt = 0; nt < 8; nt++) l[nt] = acc[mt][nt][r] + bv[nt];
      if (bn == 0 && wn == 0 && c16 == 0) blank_g[lin0 + rl] = l[0];
      if (ownL && c16 == tgc){
        float v = l[0];
#pragma unroll
        for (int k = 1; k < 8; k++) v = (ntO == k) ? l[k] : v;
        lbl_g[lin0 + rl] = v;
      }
      float s = 0.f;
#pragma unroll
      for (int nt = 0; nt < 8; nt++) s += __expf(l[nt]);
      s += __shfl_xor(s, 1, 64);
      s += __shfl_xor(s, 2, 64);
      s += __shfl_xor(s, 4, 64);
      s += __shfl_xor(s, 8, 64);
      if (c16 == 0) redS[wn][rl] = s;
    }
  }
  __syncthreads();
  if (tid < 128)
    ps[(size_t)bn * cM + lin0 + tid] = redS[0][tid] + redS[1][tid];
}

// ------------- RNN-T alpha DP, (u,t) LDS layout: diagonal reads are conflict-free -------------
// LDS index u*256+t; along diagonal t=c-u the per-lane stride is 255 = -1 mod 32.
__global__ __launch_bounds__(256) void k_dp(
    const float* __restrict__ blank_g, const float* __restrict__ lbl_g,
    const float* __restrict__ ps,
    const int* __restrict__ in_len, const int* __restrict__ tgt_len,
    float* __restrict__ afin)
{
  __shared__ float sbb[cTU];   // 65 KB
  __shared__ float slb[cTU];   // 65 KB
  int b = blockIdx.x;
  size_t base = (size_t)b * cTU;
  for (int i = threadIdx.x; i < cTU; i += 256){
    size_t g = base + i;
    float S = ps[g] + ps[(size_t)cM + g] + ps[(size_t)2 * cM + g] + ps[(size_t)3 * cM + g];
    float lse = __logf(S);
    sbb[i] = blank_g[g] - lse;
    slb[i] = ((i >> 8) < cU) ? (lbl_g[g] - lse) : NEGF;
  }
  __syncthreads();
  if (threadIdx.x >= 64) return;

  int u = threadIdx.x;                 // 0..63
  int til = in_len[b] - 1;
  int tl  = tgt_len[b];                // 32..64
  float Dprev = (u == 0) ? 0.f : NEGF; // D_d[u] = alpha[d-u][u]
  float D64prev = NEGF;
  bool cap64 = (tl == 64);
  int ub = u << 8;
  int ubm1 = (u - 1) << 8;

  auto loadB = [&](int d) -> float {
    int tb = d - 1 - u;
    bool v = (tb >= 0) & (tb <= cT - 1);
    float x = sbb[ub + (v ? tb : 0)];
    return v ? x : NEGF;
  };
  auto loadL = [&](int d) -> float {
    int t = d - u;
    bool v = (u >= 1) & (t >= 0) & (t <= cT - 1) & ((u - 1) < tl);
    float x = slb[(v ? ubm1 : 0) + (v ? t : 0)];
    return v ? x : NEGF;
  };

  float blv = loadB(1), lvv = loadL(1);     // prefetched operands for d
  for (int d = 1; d <= 319; d++){
    float blv_c = blv, lvv_c = lvv;
    blv = loadB(d + 1);                     // prefetch d+1 (off the chain)
    lvv = loadL(d + 1);
    int t = d - u;
    bool tv = (t >= 0) & (t <= cT - 1);
    float up = __shfl_up(Dprev, 1, 64);
    float term1 = Dprev + blv_c;            // NEGF operands stay hugely negative; no NaN
    float term2 = up + lvv_c;
    float Dcur = tv ? logadd(term1, term2) : NEGF;
    if (u == tl && t == til)
      afin[b] = Dcur + sbb[ub + til];
    if (cap64){
      int t64 = d - 64;
      if (t64 >= 0 && t64 <= cT - 1){
        float s63 = __shfl(Dprev, 63, 64);
        float b64v = (t64 >= 1) ? sbb[(cU << 8) + (t64 - 1)] : NEGF;
        float tA = (t64 >= 1) ? (D64prev + b64v) : NEGF;
        float tB = s63 + slb[((cU - 1) << 8) + t64];
        float D64 = logadd(tA, tB);
        if (t64 == til && u == 0)
          afin[b] = D64 + sbb[(cU << 8) + til];
        D64prev = D64;
      }
    }
    Dprev = Dcur;
  }
}

__global__ void k_final(const float* __restrict__ afin, float* __restrict__ out){
  if (threadIdx.x == 0)
    out[0] = -0.25f * (afin[0] + afin[1] + afin[2] + afin[3]);
}

extern "C" void kernel_launch(void* const* d_in, const int* in_sizes, int n_in,
                              void* d_out, int out_size, void* d_ws, size_t ws_size,
                              hipStream_t stream)
{
  (void)in_sizes; (void)n_in; (void)out_size; (void)ws_size;
  const float* inputs = (const float*)d_in[0];   // (4,256,80)
  const float* W_enc  = (const float*)d_in[1];   // (80,512)
  const float* emb    = (const float*)d_in[2];   // (1024,512)
  const float* W_jenc = (const float*)d_in[3];   // (512,512)
  const float* W_jdec = (const float*)d_in[4];   // (512,512)
  const float* b_j    = (const float*)d_in[5];   // (512)
  const float* W_out  = (const float*)d_in[6];   // (512,1024)
  const float* b_out  = (const float*)d_in[7];   // (1024)
  const int* targets  = (const int*)d_in[8];     // (4,64)
  const int* in_len   = (const int*)d_in[9];     // (4)
  const int* tgt_len  = (const int*)d_in[10];    // (4)

  char* w = (char*)d_ws;
  auto alloc = [&](size_t bytes){ char* p = w; w += (bytes + 255) & ~(size_t)255; return p; };
  float* Wcomb   = (float*)alloc((size_t)80 * 512 * 4);
  float* e       = (float*)alloc((size_t)1024 * 512 * 4);
  float* dmatb   = (float*)alloc((size_t)260 * 512 * 4);
  float* blank_g = (float*)alloc((size_t)cM * 4);
  float* lbl_g   = (float*)alloc((size_t)cM * 4);
  float* ps      = (float*)alloc((size_t)4 * cM * 4);
  float* afin    = (float*)alloc(256);
  ushort_t* Hbf  = (ushort_t*)alloc((size_t)cM * 512 * 2);
  ushort_t* WTf  = (ushort_t*)alloc((size_t)1024 * 512 * 2);

  k_pre<<<234, 256, 0, stream>>>(W_enc, W_jenc, Wcomb, emb, targets, W_jdec, b_j, dmatb,
                                 W_out, WTf);
  k_gemm_e<<<dim3(2, 256), 256, 0, stream>>>(inputs, Wcomb, e);
  k_hf<<<520, 256, 0, stream>>>(e, dmatb, Hbf);
  k_joint<<<2080, 256, 0, stream>>>(Hbf, WTf, b_out, targets, ps, blank_g, lbl_g);
  k_dp<<<4, 256, 0, stream>>>(blank_g, lbl_g, ps, in_len, tgt_len, afin);
  k_final<<<1, 64, 0, stream>>>(afin, (float*)d_out);
}

// Round 6
// 272.829 us; speedup vs baseline: 1.7795x; 1.1199x over previous
//
#include <hip/hip_runtime.h>
#include <stdint.h>

#define NEGF (-1e30f)

typedef unsigned short ushort_t;
typedef unsigned char uchar_t;
typedef __attribute__((ext_vector_type(2))) long v2i64;
typedef __attribute__((ext_vector_type(4))) float f32x4;

constexpr int cB = 4, cT = 256, cU = 64, cU1 = 65, cV = 1024, cF = 80, cH = 512, cJ = 512;
constexpr int cM = cB * cT * cU1; // 66560
constexpr int cTU = cT * cU1;     // 16640 (per-batch (u,t) plane: u*256+t)

__device__ __forceinline__ float tanh_fast(float x){
  x = fminf(15.f, fmaxf(-15.f, x));
  float e = __expf(2.f * x);
  return (e - 1.f) / (e + 1.f);
}

__device__ __forceinline__ float logadd(float x, float y){
  float m = fmaxf(x, y);
  return m + __logf(1.f + __expf(-fabsf(x - y)));
}

__device__ __forceinline__ int pk8(float a, float b, float c, float d){
  int v = __builtin_amdgcn_cvt_pk_fp8_f32(a, b, 0, false);
  v = __builtin_amdgcn_cvt_pk_fp8_f32(c, d, v, true);
  return v;
}

// ------------- fused prologue: 3 independent jobs in one dispatch -------------
// bid 0..39   : Wcomb(80,512)  = W_enc @ W_jenc
// bid 40..169 : dmatb(260,512) = emb[padded] @ W_jdec + b_j
// bid 170..201: WTf8 fp8 fragment-order transpose of 32*W_out (2-ks-packed)
__global__ __launch_bounds__(256) void k_pre(
    const float* __restrict__ W_enc, const float* __restrict__ W_jenc,
    float* __restrict__ Wcomb,
    const float* __restrict__ emb, const int* __restrict__ targets,
    const float* __restrict__ W_jdec, const float* __restrict__ b_j,
    float* __restrict__ dmatb,
    const float* __restrict__ W_out, uchar_t* __restrict__ WTf8)
{
  __shared__ float sA[4][512];
  int bid = blockIdx.x;
  int tid = threadIdx.x;

  if (bid < 170){
    bool isW = (bid < 40);
    int id = isW ? bid : bid - 40;
    int bx = id & 1, by = id >> 1;
    int m0 = by * 4;
    int col = bx * 256 + tid;
    const float* Bm = isW ? W_jenc : W_jdec;
    for (int i = tid; i < 4 * 512; i += 256){
      int r = i >> 9, c = i & 511;
      if (isW){
        sA[r][c] = W_enc[(size_t)(m0 + r) * 512 + c];
      } else {
        int row = m0 + r;
        int b = row / cU1, u = row % cU1;
        int src = (u == 0) ? 0 : targets[b * cU + (u - 1)];
        sA[r][c] = emb[(size_t)src * cH + c];
      }
    }
    __syncthreads();
    float a0 = 0.f, a1 = 0.f, a2 = 0.f, a3 = 0.f;
#pragma unroll 8
    for (int k = 0; k < 512; k++){
      float bv = Bm[(size_t)k * cJ + col];
      a0 = fmaf(sA[0][k], bv, a0);
      a1 = fmaf(sA[1][k], bv, a1);
      a2 = fmaf(sA[2][k], bv, a2);
      a3 = fmaf(sA[3][k], bv, a3);
    }
    float bb = isW ? 0.f : b_j[col];
    float* C = isW ? Wcomb : dmatb;
    C[(size_t)(m0 + 0) * cJ + col] = a0 + bb;
    C[(size_t)(m0 + 1) * cJ + col] = a1 + bb;
    C[(size_t)(m0 + 2) * cJ + col] = a2 + bb;
    C[(size_t)(m0 + 3) * cJ + col] = a3 + bb;
  } else {
    // WTf8[((bn*8+ksp)*16 + nt16)*1024 + lane*16]: 16 B = frag(ks=2ksp) || frag(ks=2ksp+1)
    // frag byte j of ks: W_out[(ks*32 + quad*8 + j)*cV + n] * 32  (fp8 scale)
    int id = bid - 170;                  // 0..31
    int bn = id & 3, ksp = id >> 2;      // ksp 0..7
    int lane = tid & 63, nth = tid >> 6;
    int c16 = lane & 15, quad = lane >> 4;
    int jA = ksp * 64 + quad * 8;
#pragma unroll
    for (int i = 0; i < 4; i++){
      int nt16 = nth * 4 + i;
      int n = bn * 256 + nt16 * 16 + c16;
      unsigned int p[4];
#pragma unroll
      for (int h = 0; h < 4; h++){
        int j0 = jA + (h >> 1) * 32 + (h & 1) * 4;
        float w0 = W_out[(size_t)(j0 + 0) * cV + n] * 32.f;
        float w1 = W_out[(size_t)(j0 + 1) * cV + n] * 32.f;
        float w2 = W_out[(size_t)(j0 + 2) * cV + n] * 32.f;
        float w3 = W_out[(size_t)(j0 + 3) * cV + n] * 32.f;
        p[h] = (unsigned)pk8(w0, w1, w2, w3);
      }
      uint4 pack; pack.x = p[0]; pack.y = p[1]; pack.z = p[2]; pack.w = p[3];
      *(uint4*)(WTf8 + (((size_t)(bn * 8 + ksp) * 16 + nt16) * 64 + lane) * 16) = pack;
    }
  }
}

// ------------- e = inputs @ Wcomb  (K=80), 4 rows/block -------------
__global__ void k_gemm_e(const float* __restrict__ A, const float* __restrict__ Bm,
                         float* __restrict__ C){
  __shared__ float sA[4][80];
  int m0 = blockIdx.y * 4;
  int col = blockIdx.x * 256 + threadIdx.x;
  for (int i = threadIdx.x; i < 4 * 80; i += 256)
    sA[i / 80][i % 80] = A[(size_t)(m0 + i / 80) * 80 + (i % 80)];
  __syncthreads();
  float a0 = 0.f, a1 = 0.f, a2 = 0.f, a3 = 0.f;
#pragma unroll 8
  for (int k = 0; k < 80; k++){
    float bv = Bm[(size_t)k * cJ + col];
    a0 = fmaf(sA[0][k], bv, a0);
    a1 = fmaf(sA[1][k], bv, a1);
    a2 = fmaf(sA[2][k], bv, a2);
    a3 = fmaf(sA[3][k], bv, a3);
  }
  C[(size_t)(m0 + 0) * cJ + col] = a0;
  C[(size_t)(m0 + 1) * cJ + col] = a1;
  C[(size_t)(m0 + 2) * cJ + col] = a2;
  C[(size_t)(m0 + 3) * cJ + col] = a3;
}

// ------------- H fp8 fragment-order, t-minor, coalesced via LDS bounce -------------
// Hbf8[((bm*8+ksp)*8 + mg)*1024 + lane*16]: row = mg*16+(lane&15) [local t],
// 16 B = frag(ks=2ksp) || frag(ks=2ksp+1); frag byte j: H[row][ks*32+(lane>>4)*8+j]
__global__ __launch_bounds__(256) void k_hf(const float* __restrict__ e,
                                            const float* __restrict__ dmatb,
                                            uchar_t* __restrict__ Hbf8){
  __shared__ uchar_t sH[16 * 520];    // 16 rows x 512 B, pad 8 B
  int tid = threadIdx.x;
  int wid = tid >> 6, lane = tid & 63;
  int c16 = lane & 15, quad = lane >> 4;
  int bm = blockIdx.x;
  int bu = bm >> 1, thalf = bm & 1;
  int b = bu / cU1;
  int t0 = thalf * 128;

  float dj[8];
  const float4* dp = (const float4*)(dmatb + (size_t)bu * cJ + lane * 8);
  float4 dA = dp[0], dB = dp[1];
  dj[0] = dA.x; dj[1] = dA.y; dj[2] = dA.z; dj[3] = dA.w;
  dj[4] = dB.x; dj[5] = dB.y; dj[6] = dB.z; dj[7] = dB.w;

  const float* erow0 = e + ((size_t)(b * cT + t0)) * cJ + lane * 8;
  uchar_t* outb = Hbf8 + (size_t)bm * 65536 + lane * 16;

  for (int mg = 0; mg < 8; mg++){
#pragma unroll
    for (int rr = 0; rr < 4; rr++){
      int rloc = wid * 4 + rr;
      const float* ep = erow0 + ((size_t)(mg * 16 + rloc)) * cJ;
      float4 e0 = *(const float4*)ep;
      float4 e1 = *(const float4*)(ep + 4);
      int v0 = pk8(tanh_fast(e0.x + dj[0]), tanh_fast(e0.y + dj[1]),
                   tanh_fast(e0.z + dj[2]), tanh_fast(e0.w + dj[3]));
      int v1 = pk8(tanh_fast(e1.x + dj[4]), tanh_fast(e1.y + dj[5]),
                   tanh_fast(e1.z + dj[6]), tanh_fast(e1.w + dj[7]));
      uint2 pk; pk.x = (unsigned)v0; pk.y = (unsigned)v1;
      *(uint2*)(sH + rloc * 520 + lane * 8) = pk;
    }
    __syncthreads();
#pragma unroll
    for (int q = 0; q < 2; q++){
      int ksp = wid * 2 + q;
      uint2 lo = *(const uint2*)(sH + c16 * 520 + ksp * 64 + quad * 8);
      uint2 hi = *(const uint2*)(sH + c16 * 520 + ksp * 64 + 32 + quad * 8);
      uint4 pack; pack.x = lo.x; pack.y = lo.y; pack.z = hi.x; pack.w = hi.y;
      *(uint4*)(outb + ((size_t)ksp * 8 + mg) * 1024) = pack;
    }
    __syncthreads();
  }
}

// ------------- joint GEMM fp8, register-resident, barrier-free K-loop -------------
// 1-D grid 2080: bm=(bid>>5)*8+(bid&7), bn=(bid>>3)&3 (XCD-coherent Hbf reuse).
// wave (wm,wn): rows [wm*64,+64) x cols [bn*256+wn*128,+128); 2 ks per 16B frag load.
__global__ __launch_bounds__(256, 2) void k_joint(
    const uchar_t* __restrict__ Hbf8, const uchar_t* __restrict__ WTf8,
    const float* __restrict__ b_out, const int* __restrict__ targets,
    float* __restrict__ ps,                       // [4][cM]
    float* __restrict__ blank_g, float* __restrict__ lbl_g)
{
  __shared__ float redS[2][128];

  int tid = threadIdx.x;
  int wid = tid >> 6, lane = tid & 63;
  int quad = lane >> 4, c16 = lane & 15;
  int wm = wid & 1, wn = wid >> 1;
  int bid = blockIdx.x;
  int bm = ((bid >> 5) << 3) + (bid & 7);
  int bn = (bid >> 3) & 3;
  int bu = bm >> 1, thalf = bm & 1;
  int b = bu / cU1, u = bu - b * cU1;
  int tg = (u < cU) ? targets[b * cU + u] : -1;
  int lin0 = bu * cT + thalf * 128;    // (b,u,t)-linear base

  f32x4 acc[4][8];
#pragma unroll
  for (int i = 0; i < 4; i++)
#pragma unroll
    for (int j = 0; j < 8; j++)
      acc[i][j] = (f32x4){0.f, 0.f, 0.f, 0.f};

  const uchar_t* aP = Hbf8 + (size_t)bm * 65536 + (wm * 4) * 1024 + lane * 16;
  const uchar_t* bP = WTf8 + (size_t)bn * 131072 + (wn * 8) * 1024 + lane * 16;

#pragma unroll
  for (int ksp = 0; ksp < 8; ksp++){
    v2i64 af[4], bf[8];
#pragma unroll
    for (int mt = 0; mt < 4; mt++)
      af[mt] = *(const v2i64*)(aP + (size_t)ksp * 8192 + mt * 1024);
#pragma unroll
    for (int nt = 0; nt < 8; nt++)
      bf[nt] = *(const v2i64*)(bP + (size_t)ksp * 16384 + nt * 1024);
#pragma unroll
    for (int h = 0; h < 2; h++)
#pragma unroll
      for (int mt = 0; mt < 4; mt++)
#pragma unroll
        for (int nt = 0; nt < 8; nt++)
          acc[mt][nt] = __builtin_amdgcn_mfma_f32_16x16x32_fp8_fp8(af[mt][h], bf[nt][h], acc[mt][nt], 0, 0, 0);
  }

  float bv[8];
#pragma unroll
  for (int nt = 0; nt < 8; nt++) bv[nt] = b_out[bn * 256 + (wn * 8 + nt) * 16 + c16];

  bool ownL = (tg >= 0) && ((tg >> 8) == bn) && ((((tg >> 4) & 15) >> 3) == wn);
  int ntO = (tg >> 4) & 7;
  int tgc = tg & 15;
  const float descale = 1.f / 32.f;     // undo the *32 on W_out fp8

#pragma unroll
  for (int mt = 0; mt < 4; mt++){
#pragma unroll
    for (int r = 0; r < 4; r++){
      int rl = wm * 64 + mt * 16 + quad * 4 + r;  // C/D: col=lane&15, row=quad*4+reg (m89)
      float l[8];
#pragma unroll
      for (int nt = 0; nt < 8; nt++) l[nt] = fmaf(acc[mt][nt][r], descale, bv[nt]);
      if (bn == 0 && wn == 0 && c16 == 0) blank_g[lin0 + rl] = l[0];
      if (ownL && c16 == tgc){
        float v = l[0];
#pragma unroll
        for (int k = 1; k < 8; k++) v = (ntO == k) ? l[k] : v;
        lbl_g[lin0 + rl] = v;
      }
      float s = 0.f;
#pragma unroll
      for (int nt = 0; nt < 8; nt++) s += __expf(l[nt]);
      s += __shfl_xor(s, 1, 64);
      s += __shfl_xor(s, 2, 64);
      s += __shfl_xor(s, 4, 64);
      s += __shfl_xor(s, 8, 64);
      if (c16 == 0) redS[wn][rl] = s;
    }
  }
  __syncthreads();
  if (tid < 128)
    ps[(size_t)bn * cM + lin0 + tid] = redS[0][tid] + redS[1][tid];
}

// ------------- RNN-T alpha DP, (u,t) LDS layout: diagonal reads conflict-free -------------
__global__ __launch_bounds__(256) void k_dp(
    const float* __restrict__ blank_g, const float* __restrict__ lbl_g,
    const float* __restrict__ ps,
    const int* __restrict__ in_len, const int* __restrict__ tgt_len,
    float* __restrict__ afin)
{
  __shared__ float sbb[cTU];   // 65 KB
  __shared__ float slb[cTU];   // 65 KB
  int b = blockIdx.x;
  size_t base = (size_t)b * cTU;
  for (int i = threadIdx.x; i < cTU; i += 256){
    size_t g = base + i;
    float S = ps[g] + ps[(size_t)cM + g] + ps[(size_t)2 * cM + g] + ps[(size_t)3 * cM + g];
    float lse = __logf(S);
    sbb[i] = blank_g[g] - lse;
    slb[i] = ((i >> 8) < cU) ? (lbl_g[g] - lse) : NEGF;
  }
  __syncthreads();
  if (threadIdx.x >= 64) return;

  int u = threadIdx.x;                 // 0..63
  int til = in_len[b] - 1;
  int tl  = tgt_len[b];                // 32..64
  float Dprev = (u == 0) ? 0.f : NEGF; // D_d[u] = alpha[d-u][u]
  float D64prev = NEGF;
  bool cap64 = (tl == 64);
  int ub = u << 8;
  int ubm1 = (u - 1) << 8;

  auto loadB = [&](int d) -> float {
    int tb = d - 1 - u;
    bool v = (tb >= 0) & (tb <= cT - 1);
    float x = sbb[ub + (v ? tb : 0)];
    return v ? x : NEGF;
  };
  auto loadL = [&](int d) -> float {
    int t = d - u;
    bool v = (u >= 1) & (t >= 0) & (t <= cT - 1) & ((u - 1) < tl);
    float x = slb[(v ? ubm1 : 0) + (v ? t : 0)];
    return v ? x : NEGF;
  };

  float blv = loadB(1), lvv = loadL(1);
  for (int d = 1; d <= 319; d++){
    float blv_c = blv, lvv_c = lvv;
    blv = loadB(d + 1);
    lvv = loadL(d + 1);
    int t = d - u;
    bool tv = (t >= 0) & (t <= cT - 1);
    float up = __shfl_up(Dprev, 1, 64);
    float term1 = Dprev + blv_c;
    float term2 = up + lvv_c;
    float Dcur = tv ? logadd(term1, term2) : NEGF;
    if (u == tl && t == til)
      afin[b] = Dcur + sbb[ub + til];
    if (cap64){
      int t64 = d - 64;
      if (t64 >= 0 && t64 <= cT - 1){
        float s63 = __shfl(Dprev, 63, 64);
        float b64v = (t64 >= 1) ? sbb[(cU << 8) + (t64 - 1)] : NEGF;
        float tA = (t64 >= 1) ? (D64prev + b64v) : NEGF;
        float tB = s63 + slb[((cU - 1) << 8) + t64];
        float D64 = logadd(tA, tB);
        if (t64 == til && u == 0)
          afin[b] = D64 + sbb[(cU << 8) + til];
        D64prev = D64;
      }
    }
    Dprev = Dcur;
  }
}

__global__ void k_final(const float* __restrict__ afin, float* __restrict__ out){
  if (threadIdx.x == 0)
    out[0] = -0.25f * (afin[0] + afin[1] + afin[2] + afin[3]);
}

extern "C" void kernel_launch(void* const* d_in, const int* in_sizes, int n_in,
                              void* d_out, int out_size, void* d_ws, size_t ws_size,
                              hipStream_t stream)
{
  (void)in_sizes; (void)n_in; (void)out_size; (void)ws_size;
  const float* inputs = (const float*)d_in[0];   // (4,256,80)
  const float* W_enc  = (const float*)d_in[1];   // (80,512)
  const float* emb    = (const float*)d_in[2];   // (1024,512)
  const float* W_jenc = (const float*)d_in[3];   // (512,512)
  const float* W_jdec = (const float*)d_in[4];   // (512,512)
  const float* b_j    = (const float*)d_in[5];   // (512)
  const float* W_out  = (const float*)d_in[6];   // (512,1024)
  const float* b_out  = (const float*)d_in[7];   // (1024)
  const int* targets  = (const int*)d_in[8];     // (4,64)
  const int* in_len   = (const int*)d_in[9];     // (4)
  const int* tgt_len  = (const int*)d_in[10];    // (4)

  char* w = (char*)d_ws;
  auto alloc = [&](size_t bytes){ char* p = w; w += (bytes + 255) & ~(size_t)255; return p; };
  float* Wcomb   = (float*)alloc((size_t)80 * 512 * 4);
  float* e       = (float*)alloc((size_t)1024 * 512 * 4);
  float* dmatb   = (float*)alloc((size_t)260 * 512 * 4);
  float* blank_g = (float*)alloc((size_t)cM * 4);
  float* lbl_g   = (float*)alloc((size_t)cM * 4);
  float* ps      = (float*)alloc((size_t)4 * cM * 4);
  float* afin    = (float*)alloc(256);
  uchar_t* Hbf8  = (uchar_t*)alloc((size_t)520 * 65536);
  uchar_t* WTf8  = (uchar_t*)alloc((size_t)4 * 131072);

  k_pre<<<202, 256, 0, stream>>>(W_enc, W_jenc, Wcomb, emb, targets, W_jdec, b_j, dmatb,
                                 W_out, WTf8);
  k_gemm_e<<<dim3(2, 256), 256, 0, stream>>>(inputs, Wcomb, e);
  k_hf<<<520, 256, 0, stream>>>(e, dmatb, Hbf8);
  k_joint<<<2080, 256, 0, stream>>>(Hbf8, WTf8, b_out, targets, ps, blank_g, lbl_g);
  k_dp<<<4, 256, 0, stream>>>(blank_g, lbl_g, ps, in_len, tgt_len, afin);
  k_final<<<1, 64, 0, stream>>>(afin, (float*)d_out);
}